// Round 9
// baseline (1021.745 us; speedup 1.0000x reference)
//
#include <hip/hip_runtime.h>
#include <hip/hip_bf16.h>
#include <type_traits>
#include <stdint.h>

typedef __hip_bfloat16 bf16;
typedef unsigned short u16t;

// B=4, L=4096, D=1024, H=4, DK=256, C=64, NC=64, KS=4
// Harness dtypes: ALL inputs fp32 (per reference setup_inputs), output fp32.
// Internal workspace intermediates: bf16 (2% absmax threshold gives headroom).

__device__ __forceinline__ float sigmoidf_(float x) { return 1.0f / (1.0f + __expf(-x)); }

__device__ __forceinline__ float bu2f(unsigned short u) {
    return __uint_as_float(((unsigned)u) << 16);
}
__device__ __forceinline__ float2 bu2f2(const unsigned short* p) {
    ushort2 t = *(const ushort2*)p;
    float2 r; r.x = bu2f(t.x); r.y = bu2f(t.y); return r;
}
__device__ __forceinline__ float4 ld4(const float* p) { return *(const float4*)p; }
__device__ __forceinline__ float4 ld4(const bf16* p) {
    ushort4 u = *(const ushort4*)p;
    float4 r;
    r.x = bu2f(u.x); r.y = bu2f(u.y); r.z = bu2f(u.z); r.w = bu2f(u.w);
    return r;
}
__device__ __forceinline__ unsigned short f2bu(float x) {
    bf16 h = __float2bfloat16(x);
    return *reinterpret_cast<unsigned short*>(&h);
}
__device__ __forceinline__ void st4(bf16* p, float a, float b, float c, float d) {
    ushort4 u = { f2bu(a), f2bu(b), f2bu(c), f2bu(d) };
    *(ushort4*)p = u;
}
__device__ __forceinline__ float b2f(bf16 h) { return __bfloat162float(h); }

// ---------------------------------------------------------------------------
// MFMA GEMM: C[M,N] = A[M,K] @ B[K,N] where Bt = B^T stored [N][K], bf16 in,
// fp32 accumulate.  128x128 tile, 256 threads (4 waves, 2x2), BK=32,
// global_load_lds width-16 staging, 16x16x32 bf16 MFMA, 4x4 frags per wave.
// Optional batching via blockIdx.z strides.  XCD-aware block swizzle (requires
// gridDim.x*gridDim.y % 8 == 0, true for all call sites: 1024 and 64).
// ---------------------------------------------------------------------------
typedef __bf16 bfv8 __attribute__((ext_vector_type(8)));
typedef float f32x4v __attribute__((ext_vector_type(4)));

// canonical addrspacecast form (compiler lowers generic->AS3 itself)
__device__ __forceinline__ void gl_lds16(const bf16* g, bf16* l) {
    __builtin_amdgcn_global_load_lds(
        (const __attribute__((address_space(1))) unsigned int*)g,
        (__attribute__((address_space(3))) unsigned int*)l,
        16, 0, 0);
}

template <typename OutT>
__global__ __launch_bounds__(256)
void mfma_gemm(const bf16* __restrict__ A, const bf16* __restrict__ Bt,
               OutT* __restrict__ Cm, int M, int N, int K,
               size_t aStride, size_t bStride, size_t cStride, int hMask)
{
    __shared__ __align__(16) bf16 As[4096];   // [128 rows][32 k] linear
    __shared__ __align__(16) bf16 Bs[4096];   // [128 n-rows][32 k] linear (B^T)
    const int z = blockIdx.z;
    A  += (size_t)z * aStride;
    Bt += (size_t)(z & hMask) * bStride;
    Cm += (size_t)z * cStride;
    const int tid = threadIdx.x;
    const int wid = tid >> 6, lane = tid & 63;
    // XCD swizzle: give each XCD a contiguous chunk of the original bid order
    const int nwg = gridDim.x * gridDim.y;
    int bid = blockIdx.y * gridDim.x + blockIdx.x;
    bid = (bid & 7) * (nwg >> 3) + (bid >> 3);
    const int bx = bid % gridDim.x, by = bid / gridDim.x;
    const int m0 = by << 7, n0 = bx << 7;
    const int wr = wid >> 1, wc = wid & 1;    // wave 2x2 over the 128x128 tile

    const int srow = tid >> 2;                // 0..63
    const int scol = (tid & 3) << 3;          // 0,8,16,24
    const bf16* agp = A  + (size_t)(m0 + srow) * K + scol;
    const bf16* bgp = Bt + (size_t)(n0 + srow) * K + scol;
    const size_t rowskip = (size_t)64 * K;
    bf16* al0 = As + wid * 512;
    bf16* al1 = As + 2048 + wid * 512;
    bf16* bl0 = Bs + wid * 512;
    bf16* bl1 = Bs + 2048 + wid * 512;

    // fragment LDS offsets: A[row = l&15][k = (l>>4)*8 + j]
    const int aoff = (wr * 64 + (lane & 15)) * 32 + ((lane >> 4) << 3);
    const int boff = (wc * 64 + (lane & 15)) * 32 + ((lane >> 4) << 3);

    const f32x4v vzero = {0.f, 0.f, 0.f, 0.f};
    f32x4v acc[4][4];
#pragma unroll
    for (int i = 0; i < 4; ++i)
#pragma unroll
        for (int j = 0; j < 4; ++j) acc[i][j] = vzero;

    for (int k0 = 0; k0 < K; k0 += 32) {
        gl_lds16(agp,           al0);
        gl_lds16(agp + rowskip, al1);
        gl_lds16(bgp,           bl0);
        gl_lds16(bgp + rowskip, bl1);
        agp += 32; bgp += 32;
        __syncthreads();
        bfv8 af[4], bfr[4];
#pragma unroll
        for (int i = 0; i < 4; ++i) {
            af[i]  = *(const bfv8*)(As + aoff + i * 16 * 32);
            bfr[i] = *(const bfv8*)(Bs + boff + i * 16 * 32);
        }
#pragma unroll
        for (int mi = 0; mi < 4; ++mi)
#pragma unroll
            for (int ni = 0; ni < 4; ++ni)
                acc[mi][ni] = __builtin_amdgcn_mfma_f32_16x16x32_bf16(
                    af[mi], bfr[ni], acc[mi][ni], 0, 0, 0);
        __syncthreads();
    }

    const int crow = (lane >> 4) << 2;
    const int ccol = lane & 15;
#pragma unroll
    for (int mi = 0; mi < 4; ++mi)
#pragma unroll
        for (int ni = 0; ni < 4; ++ni)
#pragma unroll
            for (int j = 0; j < 4; ++j) {
                size_t r = (size_t)(m0 + wr * 64 + mi * 16 + crow + j) * N
                         + (n0 + wc * 64 + ni * 16 + ccol);
                if constexpr (std::is_same<OutT, float>::value)
                    Cm[r] = acc[mi][ni][j];
                else
                    Cm[r] = __float2bfloat16(acc[mi][ni][j]);
            }
}

// fp32 -> bf16 elementwise cast (x), 8 elems/thread
__global__ __launch_bounds__(256)
void castx_kernel(const float* __restrict__ x, bf16* __restrict__ xb)
{
    size_t i = ((size_t)blockIdx.x * 256 + threadIdx.x) * 8;
    float4 a = ld4(&x[i]);
    float4 b = ld4(&x[i + 4]);
    st4(xb + i,     a.x, a.y, a.z, a.w);
    st4(xb + i + 4, b.x, b.y, b.z, b.w);
}

// fp32 [1024][1024] -> bf16 transposed [1024][1024]
__global__ __launch_bounds__(256)
void castT_kernel(const float* __restrict__ W, bf16* __restrict__ Wt)
{
    __shared__ float tile[32][33];
    const int tid = threadIdx.x;
    const int tx = tid & 31, ty = tid >> 5;   // 32 x 8
    const int c0 = blockIdx.x << 5, r0 = blockIdx.y << 5;
#pragma unroll
    for (int r = 0; r < 4; ++r)
        tile[ty + r * 8][tx] = W[(size_t)(r0 + ty + r * 8) * 1024 + c0 + tx];
    __syncthreads();
#pragma unroll
    for (int r = 0; r < 4; ++r)
        Wt[(size_t)(c0 + ty + r * 8) * 1024 + r0 + tx] =
            __float2bfloat16(tile[tx][ty + r * 8]);
}

// fp32 [4][256][256] -> bf16 per-head transposed [4][256][256]
__global__ __launch_bounds__(256)
void castTb_kernel(const float* __restrict__ W, bf16* __restrict__ Wt)
{
    __shared__ float tile[32][33];
    const int tid = threadIdx.x;
    const int tx = tid & 31, ty = tid >> 5;   // 32 x 8
    const int c0 = blockIdx.x << 5, r0 = blockIdx.y << 5;
    const size_t hb = (size_t)blockIdx.z << 16;
#pragma unroll
    for (int r = 0; r < 4; ++r)
        tile[ty + r * 8][tx] = W[hb + (size_t)(r0 + ty + r * 8) * 256 + c0 + tx];
    __syncthreads();
#pragma unroll
    for (int r = 0; r < 4; ++r)
        Wt[hb + (size_t)(c0 + ty + r * 8) * 256 + r0 + tx] =
            __float2bfloat16(tile[tx][ty + r * 8]);
}

// ---------------------------------------------------------------------------
// Depthwise conv (taps x[t-2+j], j=0..3) + SiLU + optional per-head l2norm.
// ---------------------------------------------------------------------------
__global__ __launch_bounds__(256)
void conv_kernel(const bf16* __restrict__ xin, const float* __restrict__ cw,
                 bf16* __restrict__ outc, int doNorm)
{
    const int bt = blockIdx.x;
    const int b = bt >> 12, t = bt & 4095;
    const int tid = threadIdx.x;
    const int h = tid >> 6, lane = tid & 63;
    const int i0 = lane << 2;
    const int d = (h << 8) + i0;
    float w0[4], w1[4], w2[4], w3[4];
    {
        float4 c0 = *(const float4*)&cw[(d + 0) * 4];
        float4 c1 = *(const float4*)&cw[(d + 1) * 4];
        float4 c2 = *(const float4*)&cw[(d + 2) * 4];
        float4 c3 = *(const float4*)&cw[(d + 3) * 4];
        w0[0] = c0.x; w0[1] = c0.y; w0[2] = c0.z; w0[3] = c0.w;
        w1[0] = c1.x; w1[1] = c1.y; w1[2] = c1.z; w1[3] = c1.w;
        w2[0] = c2.x; w2[1] = c2.y; w2[2] = c2.z; w2[3] = c2.w;
        w3[0] = c3.x; w3[1] = c3.y; w3[2] = c3.z; w3[3] = c3.w;
    }
    float acc[4] = {0.f, 0.f, 0.f, 0.f};
#pragma unroll
    for (int jj = 0; jj < 4; ++jj) {
        int tt = t - 2 + jj;
        if (tt >= 0 && tt < 4096) {
            float4 xr = ld4(&xin[((size_t)(b << 12) + tt) * 1024 + d]);
            acc[0] += xr.x * w0[jj];
            acc[1] += xr.y * w1[jj];
            acc[2] += xr.z * w2[jj];
            acc[3] += xr.w * w3[jj];
        }
    }
#pragma unroll
    for (int j = 0; j < 4; ++j) acc[j] *= sigmoidf_(acc[j]);
    if (doNorm) {
        float ss = acc[0]*acc[0] + acc[1]*acc[1] + acc[2]*acc[2] + acc[3]*acc[3];
#pragma unroll
        for (int off = 32; off > 0; off >>= 1) ss += __shfl_xor(ss, off);
        float r = rsqrtf(ss + 1e-6f);
        acc[0] *= r; acc[1] *= r; acc[2] *= r; acc[3] *= r;
    }
    st4(&outc[(((size_t)((b << 2) + h)) * 4096 + t) * 256 + i0],
        acc[0], acc[1], acc[2], acc[3]);
}

// ---------------------------------------------------------------------------
// beta = sigmoid(x @ Wb), stored (B*H, L) fp32.  x is fp32 input.
// ---------------------------------------------------------------------------
__global__ __launch_bounds__(256)
void beta_kernel(const float* __restrict__ x, const float* __restrict__ Wb,
                 float* __restrict__ beta)
{
    const int bt = blockIdx.x;
    const int b = bt >> 12, t = bt & 4095;
    const int tid = threadIdx.x;
    const int wv = tid >> 6;
    __shared__ float redB[4][4];
    float4 xv = *(const float4*)&x[(size_t)bt * 1024 + (tid << 2)];
    float xa[4] = {xv.x, xv.y, xv.z, xv.w};
    float a[4] = {0.f, 0.f, 0.f, 0.f};
#pragma unroll
    for (int j = 0; j < 4; ++j) {
        float4 wr = *(const float4*)&Wb[((tid << 2) + j) * 4];
        a[0] += xa[j] * wr.x; a[1] += xa[j] * wr.y;
        a[2] += xa[j] * wr.z; a[3] += xa[j] * wr.w;
    }
#pragma unroll
    for (int hh = 0; hh < 4; ++hh)
#pragma unroll
        for (int off = 32; off > 0; off >>= 1) a[hh] += __shfl_xor(a[hh], off);
    if ((tid & 63) == 0) {
        redB[wv][0] = a[0]; redB[wv][1] = a[1]; redB[wv][2] = a[2]; redB[wv][3] = a[3];
    }
    __syncthreads();
    if (tid < 4) {
        float s = redB[0][tid] + redB[1][tid] + redB[2][tid] + redB[3][tid];
        beta[((size_t)((b << 2) + tid)) * 4096 + t] = sigmoidf_(s);
    }
}

// ---------------------------------------------------------------------------
// Per-chunk kernel, 512 threads (8 waves). NO __restrict__ (kprojG aliases
// wOut).  A and attn on MFMA (k XOR-swizzled in LDS).  The u and w triangular
// solves run CONCURRENTLY on separate thread halves (tid<256: u, tid>=256: w)
// with one 64-reg state array each -> no spill.
// kprojG/wOut alias is cross-thread: u-half reads kproj BEFORE the barrier,
// w-half writes wOut AFTER it.
// ---------------------------------------------------------------------------
#define AST 68
__global__ __launch_bounds__(512)
void chunk_kernel(const bf16* kG, const bf16* vG,
                  const bf16* qG, const float* betaG,
                  const bf16* kprojG,
                  const float* fw1, const float* fb1,
                  const float* fw2, const float* fb2,
                  const float* tempG,
                  bf16* uOut, bf16* wOut,
                  bf16* attnOut, float* psiOut)
{
    __shared__ __align__(16) u16t kLs[64 * 256];   // 32,768 B, swizzled
    __shared__ __align__(16) float Abuf[64 * AST]; // 17,408 B (reused as q half)
    __shared__ float betaL[64];
    __shared__ float fluxL[648];
    __shared__ float redL[512];

    const int chunk = blockIdx.x;
    const int bh = chunk >> 6;
    const int n  = chunk & 63;
    const int h  = bh & 3;
    const int tid = threadIdx.x;
    const int wv = tid >> 6, l = tid & 63;
    const int l15 = l & 15, l4 = l >> 4;
    const size_t base = ((size_t)bh * 4096 + n * 64) * 256;
    const u16t* kg = (const u16t*)kG;
    const u16t* qg = (const u16t*)qG;
    const f32x4v vz = {0.f, 0.f, 0.f, 0.f};

    // stage k -> LDS swizzled (4 rounds x 16B per thread, 512 threads)
#pragma unroll
    for (int r = 0; r < 4; ++r) {
        int idx = r * 512 + tid;            // ushort8 index
        int c = idx >> 5, d0 = (idx & 31) << 3;
        ulonglong2 t16 = *(const ulonglong2*)&kg[base + c * 256 + d0];
        *(ulonglong2*)&kLs[c * 256 + (d0 ^ ((c & 7) << 3))] = t16;
    }
    if (tid < 64) betaL[tid] = betaG[(size_t)bh * 4096 + (n << 6) + tid];
    __syncthreads();

    // ---- A = strict_tril(beta * (k k^T)) via MFMA over 8 waves:
    // wave wv: row-block rb = wv>>1, col-pair cp = wv&1 (cols cp*32..cp*32+31)
    {
        const int rb = wv >> 1, cp = wv & 1;
        const int arow = (rb << 4) + l15;
        const int kc = l4 << 3;
        f32x4v accA[2] = {vz, vz};
#pragma unroll
        for (int ks = 0; ks < 8; ++ks) {
            const int dbase = (ks << 5) + kc;
            bfv8 afr = *(const bfv8*)&kLs[arow * 256 + (dbase ^ ((arow & 7) << 3))];
#pragma unroll
            for (int et = 0; et < 2; ++et) {
                const int brow = ((cp * 2 + et) << 4) + l15;
                bfv8 bfr = *(const bfv8*)&kLs[brow * 256 + (dbase ^ ((brow & 7) << 3))];
                accA[et] = __builtin_amdgcn_mfma_f32_16x16x32_bf16(afr, bfr, accA[et], 0, 0, 0);
            }
        }
        // C/D: row(c) = rb*16 + l4*4 + j, col(e) = (cp*2+et)*16 + l15
#pragma unroll
        for (int j = 0; j < 4; ++j) {
            const int c = (rb << 4) + (l4 << 2) + j;
            const float bc = betaL[c];
#pragma unroll
            for (int et = 0; et < 2; ++et) {
                const int e = ((cp * 2 + et) << 4) + l15;
                Abuf[c * AST + e] = (e < c) ? accA[et][j] * bc : 0.f;
            }
        }
    }
    __syncthreads();

    // ---- CONCURRENT solves: tid<256 solve (I+A)u = beta*v for column tid,
    //      tid>=256 solve (I+A)w = beta*k for column tid-256.
    const int half = tid >> 8;          // 0 = u, 1 = w
    const int ts = tid & 255;           // column index
    float st[64];
    float km = 0.f;
    if (half == 0) {
#pragma unroll
        for (int c = 0; c < 64; ++c)
            st[c] = betaL[c] * b2f(vG[base + c * 256 + ts]);
    } else {
#pragma unroll
        for (int c = 0; c < 64; ++c) {
            float kv = bu2f(kLs[c * 256 + (ts ^ ((c & 7) << 3))]);
            km += kv;
            st[c] = betaL[c] * kv;
        }
    }
#pragma unroll
    for (int c = 1; c < 64; ++c) {
        float s = 0.f;
        const int G = (c + 3) >> 2;
#pragma unroll
        for (int g = 0; g < G; ++g) {
            float4 a4 = *(const float4*)&Abuf[c * AST + (g << 2)];
            s += a4.x * st[(g << 2) + 0] + a4.y * st[(g << 2) + 1]
               + a4.z * st[(g << 2) + 2] + a4.w * st[(g << 2) + 3];
        }
        st[c] -= s;
    }

    // post-solve: u-half writes u + flux partials (incl. kprojG reads);
    // w-half publishes km.  wOut (aliases kprojG) written after the barrier.
    if (half == 0) {
        float um = 0.f, accv = 0.f;
#pragma unroll
        for (int c = 0; c < 64; ++c) {
            uOut[base + c * 256 + ts] = __float2bfloat16(st[c]);
            um += st[c];
            accv += b2f(kprojG[base + c * 256 + ts]) * st[c];
        }
        fluxL[256 + ts] = um * (1.f / 64.f);
        redL[ts] = accv;
    } else {
        fluxL[ts] = km * (1.f / 64.f);
    }
    __syncthreads();   // orders u-half's kproj reads before w-half's wOut writes
    if (half == 1) {
#pragma unroll
        for (int c = 0; c < 64; ++c)
            wOut[base + c * 256 + ts] = __float2bfloat16(st[c]);
    }
    // accv reduction over redL[0..255]
    for (int s2 = 128; s2 > 0; s2 >>= 1) {
        if (tid < s2) redL[tid] += redL[tid + s2];
        __syncthreads();
    }
    if (tid == 0) fluxL[512] = redL[0] * (1.f / 64.f) / tempG[h];
    __syncthreads();
    // flux MLP, layer 1 split 4-way across 512 threads
    {
        const int g = tid >> 7, j = tid & 127;
        const int i0 = g << 7;
        const int i1 = (g == 3) ? 513 : (i0 + 128);
        float a = 0.f;
        for (int i2 = i0; i2 < i1; ++i2) a += fluxL[i2] * fw1[i2 * 128 + j];
        redL[tid] = a;
    }
    __syncthreads();
    if (tid < 128) {
        float a = fb1[tid] + redL[tid] + redL[128 + tid] + redL[256 + tid] + redL[384 + tid];
        a *= sigmoidf_(a);
        fluxL[520 + tid] = a;
    }
    __syncthreads();
    if (tid < 64) {
        float p = fluxL[520 + tid] * fw2[tid] + fluxL[520 + 64 + tid] * fw2[64 + tid];
#pragma unroll
        for (int off = 32; off > 0; off >>= 1) p += __shfl_xor(p, off);
        if (tid == 0) {
            float ps = sigmoidf_(p + fb2[0]);
            psiOut[chunk] = fminf(0.99f, fmaxf(0.01f, ps));
        }
    }

    // ---- attn = tril(q k^T) via MFMA over 8 waves, q in 32-row halves ----
    u16t* qLs = (u16t*)Abuf;   // [32][256] swizzled, 16 KB
    const size_t abase = (size_t)chunk << 12;
    const int ct2 = wv >> 2, eq = wv & 3;   // wave: 16-row block x 16-col block
    const int qrow = (ct2 << 4) + l15;
    const int kc = l4 << 3;
    for (int hh = 0; hh < 2; ++hh) {
        __syncthreads();   // Abuf (or prior qLs) reads complete
        // stage q half: 2 rounds x 16B per thread (512 threads)
#pragma unroll
        for (int r = 0; r < 2; ++r) {
            int idx = r * 512 + tid;
            int rr = idx >> 5, d0 = (idx & 31) << 3;
            ulonglong2 t16 = *(const ulonglong2*)&qg[base + (size_t)((hh << 5) + rr) * 256 + d0];
            *(ulonglong2*)&qLs[rr * 256 + (d0 ^ ((rr & 7) << 3))] = t16;
        }
        __syncthreads();
        f32x4v accQ = vz;
#pragma unroll
        for (int ks = 0; ks < 8; ++ks) {
            const int dbase = (ks << 5) + kc;
            bfv8 qfr = *(const bfv8*)&qLs[qrow * 256 + (dbase ^ ((qrow & 7) << 3))];
            const int brow = (eq << 4) + l15;
            bfv8 bfr = *(const bfv8*)&kLs[brow * 256 + (dbase ^ ((brow & 7) << 3))];
            accQ = __builtin_amdgcn_mfma_f32_16x16x32_bf16(qfr, bfr, accQ, 0, 0, 0);
        }
#pragma unroll
        for (int j = 0; j < 4; ++j) {
            const int c = (hh << 5) + (ct2 << 4) + (l4 << 2) + j;
            const int e = (eq << 4) + l15;
            attnOut[abase + c * 64 + e] = __float2bfloat16((e <= c) ? accQ[j] : 0.f);
        }
    }
}

// ---------------------------------------------------------------------------
// In-place per-chunk transpose of k: [bh][n][64 c][256 d] -> [bh][n][256 d][64 c]
// (k is only consumed by scan_kernel after this point)
// ---------------------------------------------------------------------------
#define KTS 260
__global__ __launch_bounds__(256)
void ktr_kernel(bf16* kG)
{
    __shared__ u16t tile[64 * KTS];   // 33,280 B (pad 260 breaks stride-1024 banks)
    const size_t base = (size_t)blockIdx.x << 14;   // chunk * 16384 elems
    const int tid = threadIdx.x;
    u16t* kg = (u16t*)kG;
#pragma unroll
    for (int r = 0; r < 16; ++r) {
        int e4 = r * 256 + tid;
        int c = e4 >> 6, dd = (e4 & 63) << 2;
        ushort4 t4 = *(const ushort4*)&kg[base + c * 256 + dd];
        *(ushort4*)&tile[c * KTS + dd] = t4;
    }
    __syncthreads();
#pragma unroll
    for (int r = 0; r < 16; ++r) {
        int e4 = r * 256 + tid;
        int d = e4 >> 4, cc = (e4 & 15) << 2;
        ushort4 o4;
        o4.x = tile[(cc + 0) * KTS + d];
        o4.y = tile[(cc + 1) * KTS + d];
        o4.z = tile[(cc + 2) * KTS + d];
        o4.w = tile[(cc + 3) * KTS + d];
        *(ushort4*)&kg[base + d * 64 + cc] = o4;
    }
}

// ---------------------------------------------------------------------------
// MFMA scan over 64 chunks, SOFTWARE-PIPELINED. One block per (b,h,vslab16)
// = 256 blocks, 4 waves.  State Sf/Ss in registers in the dS^T C/D layout.
// Load scheduling (every __syncthreads drains vmcnt(0), so loads only hide
// within one barrier interval):
//   - qA/aA/kB (consumed in C): issued at B-interval head -> hidden under
//     phase B's ds_reads+MFMAs, drained at barrier-B.
//   - wA/u4 (consumed in B): double-buffered cross-chunk; issued at
//     C-interval head for chunk n+1 -> hidden under phase C + phase A(n+1),
//     drained at barrier-A(n+1).
// Manual 2x unroll with named register sets (no runtime-indexed frags).
// ---------------------------------------------------------------------------
__device__ __forceinline__ void scan_step(
    int nn, bool last,
    bfv8 (&WAc)[8], ushort4& U4c, bfv8 (&WAn)[8], ushort4& U4n,
    f32x4v (&Sf)[4], f32x4v (&Ss)[4],
    const bf16* __restrict__ qG, const bf16* __restrict__ kTG,
    const bf16* __restrict__ wG, const bf16* __restrict__ uG,
    const bf16* __restrict__ attnG, const float* __restrict__ psiG,
    bf16* __restrict__ oG, u16t* ssumT, u16t* uiT,
    size_t bhbase, int bh, int v0, int wv, int l15, int l4,
    int cA, int cO, int kcol, int sw15, float lf, float ls)
{
    const f32x4v vzero = {0.f, 0.f, 0.f, 0.f};
    const size_t base = bhbase + ((size_t)nn << 14);
    const size_t ab = (size_t)((bh << 6) + nn) << 12;
    const float p = psiG[(bh << 6) + nn];

    // ---- phase A: publish Ssum^T (pre-update state) ----
#pragma unroll
    for (int t = 0; t < 4; ++t) {
        const int d = (((wv << 2) + t) << 4) + l15;
        f32x4v sv = Sf[t] + Ss[t];
#pragma unroll
        for (int j = 0; j < 4; ++j) {
            const int v = (l4 << 2) + j;
            ssumT[v * 256 + (d ^ ((v & 7) << 3))] = f2bu(sv[j]);
        }
    }
    __syncthreads();   // drains WAc/U4c (in flight since previous C head)

    // ---- phase B head: issue this chunk's C-phase operands ----
    bfv8 qA[8], aA[2], kB[4][2];
#pragma unroll
    for (int ks = 0; ks < 8; ++ks)
        qA[ks] = *(const bfv8*)&qG[base + (size_t)cA * 256 + (ks << 5) + kcol];
#pragma unroll
    for (int ks = 0; ks < 2; ++ks)
        aA[ks] = *(const bfv8*)&attnG[ab + cA * 64 + (ks << 5) + kcol];
#pragma unroll
    for (int t = 0; t < 4; ++t) {
        const int d = (((wv << 2) + t) << 4) + l15;
        kB[t][0] = *(const bfv8*)&kTG[base + d * 64 + kcol];
        kB[t][1] = *(const bfv8*)&kTG[base + d * 64 + 32 + kcol];
    }

    // ---- phase B: T = w @ Ssum ; u_i = u - T ; write u_i^T ----
    bfv8 sB[8];
#pragma unroll
    for (int ks = 0; ks < 8; ++ks)
        sB[ks] = *(const bfv8*)&ssumT[l15 * 256 + (((ks << 5) + kcol) ^ sw15)];
    f32x4v T = vzero;
#pragma unroll
    for (int ks = 0; ks < 8; ++ks)
        T = __builtin_amdgcn_mfma_f32_16x16x32_bf16(WAc[ks], sB[ks], T, 0, 0, 0);
    {
        ushort4 uw;
        uw.x = f2bu(bu2f(U4c.x) - T[0]); uw.y = f2bu(bu2f(U4c.y) - T[1]);
        uw.z = f2bu(bu2f(U4c.z) - T[2]); uw.w = f2bu(bu2f(U4c.w) - T[3]);
        *(ushort4*)&uiT[l15 * 64 + (cO ^ sw15)] = uw;
    }
    __syncthreads();   // drains qA/aA/kB (hidden under phase B)

    // ---- phase C head: issue NEXT chunk's wA/u4 (double buffer) ----
    {
        const int np = last ? nn : nn + 1;
        const size_t bn = bhbase + ((size_t)np << 14);
#pragma unroll
        for (int ks = 0; ks < 8; ++ks)
            WAn[ks] = *(const bfv8*)&wG[bn + (size_t)cA * 256 + (ks << 5) + kcol];
        const u16t* ug = (const u16t*)uG;
        U4n.x = ug[bn + (size_t)(cO + 0) * 256 + v0 + l15];
        U4n.y = ug[bn + (size_t)(cO + 1) * 256 + v0 + l15];
        U4n.z = ug[bn + (size_t)(cO + 2) * 256 + v0 + l15];
        U4n.w = ug[bn + (size_t)(cO + 3) * 256 + v0 + l15];
    }

    // ---- phase C: o = q@Ssum + attn@u_i ; dS^T = u_i^T @ k ; update ----
    bfv8 uT[2];
    uT[0] = *(const bfv8*)&uiT[l15 * 64 + (kcol ^ sw15)];
    uT[1] = *(const bfv8*)&uiT[l15 * 64 + ((32 + kcol) ^ sw15)];
    f32x4v oa = vzero;
    oa = __builtin_amdgcn_mfma_f32_16x16x32_bf16(aA[0], uT[0], oa, 0, 0, 0);
    oa = __builtin_amdgcn_mfma_f32_16x16x32_bf16(aA[1], uT[1], oa, 0, 0, 0);
#pragma unroll
    for (int ks = 0; ks < 8; ++ks)
        oa = __builtin_amdgcn_mfma_f32_16x16x32_bf16(qA[ks], sB[ks], oa, 0, 0, 0);
#pragma unroll
    for (int j = 0; j < 4; ++j)
        oG[base + (size_t)(cO + j) * 256 + v0 + l15] = __float2bfloat16(oa[j]);
    const float pn = 1.f - p;
#pragma unroll
    for (int t = 0; t < 4; ++t) {
        f32x4v ds = vzero;
        ds = __builtin_amdgcn_mfma_f32_16x16x32_bf16(uT[0], kB[t][0], ds, 0, 0, 0);
        ds = __builtin_amdgcn_mfma_f32_16x16x32_bf16(uT[1], kB[t][1], ds, 0, 0, 0);
        Sf[t] = lf * Sf[t] + p  * ds;
        Ss[t] = ls * Ss[t] + pn * ds;
    }
    // no barrier at chunk end: next phase-A write is ordered by barrier-B
    // (all waves' ssumT reads completed before it)
}

__global__ __launch_bounds__(256, 1)
void scan_kernel(const bf16* __restrict__ qG, const bf16* __restrict__ kTG,
                 const bf16* __restrict__ wG, const bf16* __restrict__ uG,
                 const bf16* __restrict__ attnG, const float* __restrict__ psiG,
                 const float* __restrict__ lamF, const float* __restrict__ lamS,
                 bf16* __restrict__ oG)
{
    __shared__ __align__(16) u16t ssumT[16 * 256];  // [v][swz(v,d)]  8 KB
    __shared__ __align__(16) u16t uiT[16 * 64];     // [v][swz(v,c)]  2 KB

    const int bidx = blockIdx.x;
    const int bh = bidx >> 4, vb = bidx & 15;
    const int h = bh & 3;
    const int v0 = vb << 4;
    const int tid = threadIdx.x;
    const int wv = tid >> 6, l = tid & 63;
    const int l15 = l & 15, l4 = l >> 4;
    const float lf = lamF[h], ls = lamS[h];

    const int cA   = (wv << 4) + l15;        // A-operand row (c) for w,q,attn
    const int cO   = (wv << 4) + (l4 << 2);  // C/D output row base (c)
    const int kcol = l4 << 3;                // k-offset within a 32-step
    const int sw15 = (l15 & 7) << 3;         // swizzle term for row l15

    const f32x4v vzero = {0.f, 0.f, 0.f, 0.f};
    f32x4v Sf[4], Ss[4];
#pragma unroll
    for (int t = 0; t < 4; ++t) { Sf[t] = vzero; Ss[t] = vzero; }

    const size_t bhbase = (size_t)bh * 4096 * 256;

    // prologue: load chunk 0's wA/u4
    bfv8 wA0[8], wA1[8];
    ushort4 u40, u41;
    {
#pragma unroll
        for (int ks = 0; ks < 8; ++ks)
            wA0[ks] = *(const bfv8*)&wG[bhbase + (size_t)cA * 256 + (ks << 5) + kcol];
        const u16t* ug = (const u16t*)uG;
        u40.x = ug[bhbase + (size_t)(cO + 0) * 256 + v0 + l15];
        u40.y = ug[bhbase + (size_t)(cO + 1) * 256 + v0 + l15];
        u40.z = ug[bhbase + (size_t)(cO + 2) * 256 + v0 + l15];
        u40.w = ug[bhbase + (size_t)(cO + 3) * 256 + v0 + l15];
    }

    for (int n = 0; n < 64; n += 2) {
        scan_step(n,     false,     wA0, u40, wA1, u41, Sf, Ss,
                  qG, kTG, wG, uG, attnG, psiG, oG, ssumT, uiT,
                  bhbase, bh, v0, wv, l15, l4, cA, cO, kcol, sw15, lf, ls);
        scan_step(n + 1, n + 1 == 63, wA1, u41, wA0, u40, Sf, Ss,
                  qG, kTG, wG, uG, attnG, psiG, oG, ssumT, uiT,
                  bhbase, bh, v0, wv, l15, l4, cA, cO, kcol, sw15, lf, ls);
    }
}

// ---------------------------------------------------------------------------
// Final RMSNorm * rms_w * sigmoid(g): chunked o -> natural (B,L,D) bf16
// ---------------------------------------------------------------------------
__global__ __launch_bounds__(256)
void fnorm_kernel(const bf16* __restrict__ oS, const bf16* __restrict__ xg,
                  const float* __restrict__ rmsw, bf16* __restrict__ outn)
{
    const int bt = blockIdx.x;
    const int b = bt >> 12, t = bt & 4095;
    const int tid = threadIdx.x;
    const int h = tid >> 6, lane = tid & 63;
    const int i0 = lane << 2;
    float4 o4 = ld4(&oS[(((size_t)((b << 2) + h)) * 4096 + t) * 256 + i0]);
    float ss = o4.x * o4.x + o4.y * o4.y + o4.z * o4.z + o4.w * o4.w;
#pragma unroll
    for (int off = 32; off > 0; off >>= 1) ss += __shfl_xor(ss, off);
    float r = rsqrtf(ss * (1.f / 256.f) + 1e-5f);
    float4 g4 = ld4(&xg[(size_t)bt * 1024 + (h << 8) + i0]);
    float4 w4 = *(const float4*)&rmsw[i0];
    st4(&outn[(size_t)bt * 1024 + (h << 8) + i0],
        o4.x * r * w4.x * sigmoidf_(g4.x),
        o4.y * r * w4.y * sigmoidf_(g4.y),
        o4.z * r * w4.z * sigmoidf_(g4.z),
        o4.w * r * w4.w * sigmoidf_(g4.w));
}

// ---------------------------------------------------------------------------
extern "C" void kernel_launch(void* const* d_in, const int* in_sizes, int n_in,
                              void* d_out, int out_size, void* d_ws, size_t ws_size,
                              hipStream_t stream)
{
    const float* x    = (const float*)d_in[0];
    const float* Wq   = (const float*)d_in[1];
    const float* Wk   = (const float*)d_in[2];
    const float* Wv   = (const float*)d_in[3];
    const float* Wb   = (const float*)d_in[4];
    const float* Wg   = (const float*)d_in[5];
    const float* Wo   = (const float*)d_in[6];
    const float* cq   = (const float*)d_in[7];
    const float* ck   = (const float*)d_in[8];
    const float* cv   = (const float*)d_in[9];
    const float* Wbil = (const float*)d_in[10];
    const float* temp = (const float*)d_in[11];
    const float* fw1  = (const float*)d_in[12];
    const float* fb1  = (const float*)d_in[13];
    const float* fw2  = (const float*)d_in[14];
    const float* fb2  = (const float*)d_in[15];
    const float* rmsw = (const float*)d_in[16];
    const float* lamF = (const float*)d_in[17];
    const float* lamS = (const float*)d_in[18];
    float* out = (float*)d_out;   // fp32 output, per reference dtype

    const size_t SZ = 16777216ull;             // elems per (B,H,L,DK) slab
    bf16* bws = (bf16*)d_ws;
    bf16* S0 = bws;                            // proj scratch -> g
    bf16* S1 = bws + SZ;                       // q -> onorm
    bf16* S2 = bws + 2 * SZ;                   // k (-> kT in place)
    bf16* S3 = bws + 3 * SZ;                   // v -> o
    bf16* S4 = bws + 4 * SZ;                   // kproj -> w
    bf16* S5 = bws + 5 * SZ;                   // x(bf16) -> u
    bf16* attnB = bws + 6 * SZ;                // 4,194,304 elems (8MB)
    float* p_beta = (float*)(bws + 6 * SZ + 4194304);  // 65,536 fp32
    float* p_psi  = p_beta + 65536;            // 1,024 fp32
    // total ~200.3 MB (unchanged)

    // transposed-bf16 weights live in attnB until chunk_kernel overwrites it
    bf16* Wqt = attnB;
    bf16* Wkt = attnB + 1048576;
    bf16* Wvt = attnB + 2097152;
    bf16* Wgt = attnB + 3145728;

    castx_kernel<<<8192, 256, 0, stream>>>(x, S5);
    castT_kernel<<<dim3(32, 32), 256, 0, stream>>>(Wq, Wqt);
    castT_kernel<<<dim3(32, 32), 256, 0, stream>>>(Wk, Wkt);
    castT_kernel<<<dim3(32, 32), 256, 0, stream>>>(Wv, Wvt);
    castT_kernel<<<dim3(32, 32), 256, 0, stream>>>(Wg, Wgt);

    dim3 gM(8, 128);   // (N/128, M/128)
    mfma_gemm<bf16><<<gM, 256, 0, stream>>>(S5, Wqt, S0, 16384, 1024, 1024, 0, 0, 0, 0);
    conv_kernel<<<16384, 256, 0, stream>>>(S0, cq, S1, 1);
    mfma_gemm<bf16><<<gM, 256, 0, stream>>>(S5, Wkt, S0, 16384, 1024, 1024, 0, 0, 0, 0);
    conv_kernel<<<16384, 256, 0, stream>>>(S0, ck, S2, 1);
    mfma_gemm<bf16><<<gM, 256, 0, stream>>>(S5, Wvt, S0, 16384, 1024, 1024, 0, 0, 0, 0);
    conv_kernel<<<16384, 256, 0, stream>>>(S0, cv, S3, 0);
    mfma_gemm<bf16><<<gM, 256, 0, stream>>>(S5, Wgt, S0, 16384, 1024, 1024, 0, 0, 0, 0);
    beta_kernel<<<16384, 256, 0, stream>>>(x, Wb, p_beta);

    // Wbil -> per-head transposed bf16 (reuse attnB scratch; all Wqt..Wgt
    // reads are complete after the last mfma_gemm above)
    bf16* Wbilt = attnB;
    castTb_kernel<<<dim3(8, 8, 4), 256, 0, stream>>>(Wbil, Wbilt);
    // kproj = k @ Wbil[h] on MFMA: batched z=16, M=4096, N=256, K=256
    mfma_gemm<bf16><<<dim3(2, 32, 16), 256, 0, stream>>>(
        S2, Wbilt, S4, 4096, 256, 256, 1048576ull, 65536ull, 1048576ull, 3);
    chunk_kernel<<<1024, 512, 0, stream>>>(
        S2, S3, S1, p_beta, S4, fw1, fb1, fw2, fb2, temp,
        S5 /*u*/, S4 /*w*/, attnB, p_psi);
    ktr_kernel<<<1024, 256, 0, stream>>>(S2);    // k -> kT in place
    scan_kernel<<<256, 256, 0, stream>>>(
        S1, S2, S4, S5, attnB, p_psi, lamF, lamS, S3 /*o*/);
    // attnB free after scan: reuse for transposed-bf16 Wo
    castT_kernel<<<dim3(32, 32), 256, 0, stream>>>(Wo, attnB);
    fnorm_kernel<<<16384, 256, 0, stream>>>(S3, S0, rmsw, S1);
    mfma_gemm<float><<<gM, 256, 0, stream>>>(S1, attnB, out, 16384, 1024, 1024, 0, 0, 0, 0);
}

// Round 10
// 1015.417 us; speedup vs baseline: 1.0062x; 1.0062x over previous
//
#include <hip/hip_runtime.h>
#include <hip/hip_bf16.h>
#include <type_traits>
#include <stdint.h>

typedef __hip_bfloat16 bf16;
typedef unsigned short u16t;

// B=4, L=4096, D=1024, H=4, DK=256, C=64, NC=64, KS=4
// Harness dtypes: ALL inputs fp32 (per reference setup_inputs), output fp32.
// Internal workspace intermediates: bf16 (2% absmax threshold gives headroom).

__device__ __forceinline__ float sigmoidf_(float x) { return 1.0f / (1.0f + __expf(-x)); }

__device__ __forceinline__ float bu2f(unsigned short u) {
    return __uint_as_float(((unsigned)u) << 16);
}
__device__ __forceinline__ float2 bu2f2(const unsigned short* p) {
    ushort2 t = *(const ushort2*)p;
    float2 r; r.x = bu2f(t.x); r.y = bu2f(t.y); return r;
}
__device__ __forceinline__ float4 ld4(const float* p) { return *(const float4*)p; }
__device__ __forceinline__ float4 ld4(const bf16* p) {
    ushort4 u = *(const ushort4*)p;
    float4 r;
    r.x = bu2f(u.x); r.y = bu2f(u.y); r.z = bu2f(u.z); r.w = bu2f(u.w);
    return r;
}
__device__ __forceinline__ unsigned short f2bu(float x) {
    bf16 h = __float2bfloat16(x);
    return *reinterpret_cast<unsigned short*>(&h);
}
__device__ __forceinline__ void st4(bf16* p, float a, float b, float c, float d) {
    ushort4 u = { f2bu(a), f2bu(b), f2bu(c), f2bu(d) };
    *(ushort4*)p = u;
}
__device__ __forceinline__ float b2f(bf16 h) { return __bfloat162float(h); }

// ---------------------------------------------------------------------------
// MFMA GEMM: C[M,N] = A[M,K] @ B[K,N] where Bt = B^T stored [N][K], bf16 in,
// fp32 accumulate.  128x128 tile, 256 threads (4 waves, 2x2), BK=32,
// global_load_lds width-16 staging, 16x16x32 bf16 MFMA, 4x4 frags per wave.
// Optional batching via blockIdx.z strides.  XCD-aware block swizzle (requires
// gridDim.x*gridDim.y % 8 == 0, true for all call sites: 1024 and 64).
// ---------------------------------------------------------------------------
typedef __bf16 bfv8 __attribute__((ext_vector_type(8)));
typedef float f32x4v __attribute__((ext_vector_type(4)));

// canonical addrspacecast form (compiler lowers generic->AS3 itself)
__device__ __forceinline__ void gl_lds16(const bf16* g, bf16* l) {
    __builtin_amdgcn_global_load_lds(
        (const __attribute__((address_space(1))) unsigned int*)g,
        (__attribute__((address_space(3))) unsigned int*)l,
        16, 0, 0);
}

template <typename OutT>
__global__ __launch_bounds__(256)
void mfma_gemm(const bf16* __restrict__ A, const bf16* __restrict__ Bt,
               OutT* __restrict__ Cm, int M, int N, int K,
               size_t aStride, size_t bStride, size_t cStride, int hMask)
{
    __shared__ __align__(16) bf16 As[4096];   // [128 rows][32 k] linear
    __shared__ __align__(16) bf16 Bs[4096];   // [128 n-rows][32 k] linear (B^T)
    const int z = blockIdx.z;
    A  += (size_t)z * aStride;
    Bt += (size_t)(z & hMask) * bStride;
    Cm += (size_t)z * cStride;
    const int tid = threadIdx.x;
    const int wid = tid >> 6, lane = tid & 63;
    // XCD swizzle: give each XCD a contiguous chunk of the original bid order
    const int nwg = gridDim.x * gridDim.y;
    int bid = blockIdx.y * gridDim.x + blockIdx.x;
    bid = (bid & 7) * (nwg >> 3) + (bid >> 3);
    const int bx = bid % gridDim.x, by = bid / gridDim.x;
    const int m0 = by << 7, n0 = bx << 7;
    const int wr = wid >> 1, wc = wid & 1;    // wave 2x2 over the 128x128 tile

    const int srow = tid >> 2;                // 0..63
    const int scol = (tid & 3) << 3;          // 0,8,16,24
    const bf16* agp = A  + (size_t)(m0 + srow) * K + scol;
    const bf16* bgp = Bt + (size_t)(n0 + srow) * K + scol;
    const size_t rowskip = (size_t)64 * K;
    bf16* al0 = As + wid * 512;
    bf16* al1 = As + 2048 + wid * 512;
    bf16* bl0 = Bs + wid * 512;
    bf16* bl1 = Bs + 2048 + wid * 512;

    // fragment LDS offsets: A[row = l&15][k = (l>>4)*8 + j]
    const int aoff = (wr * 64 + (lane & 15)) * 32 + ((lane >> 4) << 3);
    const int boff = (wc * 64 + (lane & 15)) * 32 + ((lane >> 4) << 3);

    const f32x4v vzero = {0.f, 0.f, 0.f, 0.f};
    f32x4v acc[4][4];
#pragma unroll
    for (int i = 0; i < 4; ++i)
#pragma unroll
        for (int j = 0; j < 4; ++j) acc[i][j] = vzero;

    for (int k0 = 0; k0 < K; k0 += 32) {
        gl_lds16(agp,           al0);
        gl_lds16(agp + rowskip, al1);
        gl_lds16(bgp,           bl0);
        gl_lds16(bgp + rowskip, bl1);
        agp += 32; bgp += 32;
        __syncthreads();
        bfv8 af[4], bfr[4];
#pragma unroll
        for (int i = 0; i < 4; ++i) {
            af[i]  = *(const bfv8*)(As + aoff + i * 16 * 32);
            bfr[i] = *(const bfv8*)(Bs + boff + i * 16 * 32);
        }
#pragma unroll
        for (int mi = 0; mi < 4; ++mi)
#pragma unroll
            for (int ni = 0; ni < 4; ++ni)
                acc[mi][ni] = __builtin_amdgcn_mfma_f32_16x16x32_bf16(
                    af[mi], bfr[ni], acc[mi][ni], 0, 0, 0);
        __syncthreads();
    }

    const int crow = (lane >> 4) << 2;
    const int ccol = lane & 15;
#pragma unroll
    for (int mi = 0; mi < 4; ++mi)
#pragma unroll
        for (int ni = 0; ni < 4; ++ni)
#pragma unroll
            for (int j = 0; j < 4; ++j) {
                size_t r = (size_t)(m0 + wr * 64 + mi * 16 + crow + j) * N
                         + (n0 + wc * 64 + ni * 16 + ccol);
                if constexpr (std::is_same<OutT, float>::value)
                    Cm[r] = acc[mi][ni][j];
                else
                    Cm[r] = __float2bfloat16(acc[mi][ni][j]);
            }
}

// fp32 -> bf16 elementwise cast (x), 8 elems/thread
__global__ __launch_bounds__(256)
void castx_kernel(const float* __restrict__ x, bf16* __restrict__ xb)
{
    size_t i = ((size_t)blockIdx.x * 256 + threadIdx.x) * 8;
    float4 a = ld4(&x[i]);
    float4 b = ld4(&x[i + 4]);
    st4(xb + i,     a.x, a.y, a.z, a.w);
    st4(xb + i + 4, b.x, b.y, b.z, b.w);
}

// fp32 [1024][1024] -> bf16 transposed [1024][1024]
__global__ __launch_bounds__(256)
void castT_kernel(const float* __restrict__ W, bf16* __restrict__ Wt)
{
    __shared__ float tile[32][33];
    const int tid = threadIdx.x;
    const int tx = tid & 31, ty = tid >> 5;   // 32 x 8
    const int c0 = blockIdx.x << 5, r0 = blockIdx.y << 5;
#pragma unroll
    for (int r = 0; r < 4; ++r)
        tile[ty + r * 8][tx] = W[(size_t)(r0 + ty + r * 8) * 1024 + c0 + tx];
    __syncthreads();
#pragma unroll
    for (int r = 0; r < 4; ++r)
        Wt[(size_t)(c0 + ty + r * 8) * 1024 + r0 + tx] =
            __float2bfloat16(tile[tx][ty + r * 8]);
}

// fp32 [4][256][256] -> bf16 per-head transposed [4][256][256]
__global__ __launch_bounds__(256)
void castTb_kernel(const float* __restrict__ W, bf16* __restrict__ Wt)
{
    __shared__ float tile[32][33];
    const int tid = threadIdx.x;
    const int tx = tid & 31, ty = tid >> 5;   // 32 x 8
    const int c0 = blockIdx.x << 5, r0 = blockIdx.y << 5;
    const size_t hb = (size_t)blockIdx.z << 16;
#pragma unroll
    for (int r = 0; r < 4; ++r)
        tile[ty + r * 8][tx] = W[hb + (size_t)(r0 + ty + r * 8) * 256 + c0 + tx];
    __syncthreads();
#pragma unroll
    for (int r = 0; r < 4; ++r)
        Wt[hb + (size_t)(c0 + ty + r * 8) * 256 + r0 + tx] =
            __float2bfloat16(tile[tx][ty + r * 8]);
}

// ---------------------------------------------------------------------------
// Depthwise conv (taps x[t-2+j], j=0..3) + SiLU + optional per-head l2norm.
// ---------------------------------------------------------------------------
__global__ __launch_bounds__(256)
void conv_kernel(const bf16* __restrict__ xin, const float* __restrict__ cw,
                 bf16* __restrict__ outc, int doNorm)
{
    const int bt = blockIdx.x;
    const int b = bt >> 12, t = bt & 4095;
    const int tid = threadIdx.x;
    const int h = tid >> 6, lane = tid & 63;
    const int i0 = lane << 2;
    const int d = (h << 8) + i0;
    float w0[4], w1[4], w2[4], w3[4];
    {
        float4 c0 = *(const float4*)&cw[(d + 0) * 4];
        float4 c1 = *(const float4*)&cw[(d + 1) * 4];
        float4 c2 = *(const float4*)&cw[(d + 2) * 4];
        float4 c3 = *(const float4*)&cw[(d + 3) * 4];
        w0[0] = c0.x; w0[1] = c0.y; w0[2] = c0.z; w0[3] = c0.w;
        w1[0] = c1.x; w1[1] = c1.y; w1[2] = c1.z; w1[3] = c1.w;
        w2[0] = c2.x; w2[1] = c2.y; w2[2] = c2.z; w2[3] = c2.w;
        w3[0] = c3.x; w3[1] = c3.y; w3[2] = c3.z; w3[3] = c3.w;
    }
    float acc[4] = {0.f, 0.f, 0.f, 0.f};
#pragma unroll
    for (int jj = 0; jj < 4; ++jj) {
        int tt = t - 2 + jj;
        if (tt >= 0 && tt < 4096) {
            float4 xr = ld4(&xin[((size_t)(b << 12) + tt) * 1024 + d]);
            acc[0] += xr.x * w0[jj];
            acc[1] += xr.y * w1[jj];
            acc[2] += xr.z * w2[jj];
            acc[3] += xr.w * w3[jj];
        }
    }
#pragma unroll
    for (int j = 0; j < 4; ++j) acc[j] *= sigmoidf_(acc[j]);
    if (doNorm) {
        float ss = acc[0]*acc[0] + acc[1]*acc[1] + acc[2]*acc[2] + acc[3]*acc[3];
#pragma unroll
        for (int off = 32; off > 0; off >>= 1) ss += __shfl_xor(ss, off);
        float r = rsqrtf(ss + 1e-6f);
        acc[0] *= r; acc[1] *= r; acc[2] *= r; acc[3] *= r;
    }
    st4(&outc[(((size_t)((b << 2) + h)) * 4096 + t) * 256 + i0],
        acc[0], acc[1], acc[2], acc[3]);
}

// ---------------------------------------------------------------------------
// beta = sigmoid(x @ Wb), stored (B*H, L) fp32.  x is fp32 input.
// ---------------------------------------------------------------------------
__global__ __launch_bounds__(256)
void beta_kernel(const float* __restrict__ x, const float* __restrict__ Wb,
                 float* __restrict__ beta)
{
    const int bt = blockIdx.x;
    const int b = bt >> 12, t = bt & 4095;
    const int tid = threadIdx.x;
    const int wv = tid >> 6;
    __shared__ float redB[4][4];
    float4 xv = *(const float4*)&x[(size_t)bt * 1024 + (tid << 2)];
    float xa[4] = {xv.x, xv.y, xv.z, xv.w};
    float a[4] = {0.f, 0.f, 0.f, 0.f};
#pragma unroll
    for (int j = 0; j < 4; ++j) {
        float4 wr = *(const float4*)&Wb[((tid << 2) + j) * 4];
        a[0] += xa[j] * wr.x; a[1] += xa[j] * wr.y;
        a[2] += xa[j] * wr.z; a[3] += xa[j] * wr.w;
    }
#pragma unroll
    for (int hh = 0; hh < 4; ++hh)
#pragma unroll
        for (int off = 32; off > 0; off >>= 1) a[hh] += __shfl_xor(a[hh], off);
    if ((tid & 63) == 0) {
        redB[wv][0] = a[0]; redB[wv][1] = a[1]; redB[wv][2] = a[2]; redB[wv][3] = a[3];
    }
    __syncthreads();
    if (tid < 4) {
        float s = redB[0][tid] + redB[1][tid] + redB[2][tid] + redB[3][tid];
        beta[((size_t)((b << 2) + tid)) * 4096 + t] = sigmoidf_(s);
    }
}

// ---------------------------------------------------------------------------
// Per-chunk kernel, 512 threads (8 waves). NO __restrict__ (kprojG aliases
// wOut).  A and attn on MFMA (k XOR-swizzled in LDS).  The u and w triangular
// solves run CONCURRENTLY on separate thread halves (tid<256: u, tid>=256: w)
// with one 64-reg state array each -> no spill.
// kprojG/wOut alias is cross-thread: u-half reads kproj BEFORE the barrier,
// w-half writes wOut AFTER it.
// ---------------------------------------------------------------------------
#define AST 68
__global__ __launch_bounds__(512)
void chunk_kernel(const bf16* kG, const bf16* vG,
                  const bf16* qG, const float* betaG,
                  const bf16* kprojG,
                  const float* fw1, const float* fb1,
                  const float* fw2, const float* fb2,
                  const float* tempG,
                  bf16* uOut, bf16* wOut,
                  bf16* attnOut, float* psiOut)
{
    __shared__ __align__(16) u16t kLs[64 * 256];   // 32,768 B, swizzled
    __shared__ __align__(16) float Abuf[64 * AST]; // 17,408 B (reused as q half)
    __shared__ float betaL[64];
    __shared__ float fluxL[648];
    __shared__ float redL[512];

    const int chunk = blockIdx.x;
    const int bh = chunk >> 6;
    const int n  = chunk & 63;
    const int h  = bh & 3;
    const int tid = threadIdx.x;
    const int wv = tid >> 6, l = tid & 63;
    const int l15 = l & 15, l4 = l >> 4;
    const size_t base = ((size_t)bh * 4096 + n * 64) * 256;
    const u16t* kg = (const u16t*)kG;
    const u16t* qg = (const u16t*)qG;
    const f32x4v vz = {0.f, 0.f, 0.f, 0.f};

    // stage k -> LDS swizzled (4 rounds x 16B per thread, 512 threads)
#pragma unroll
    for (int r = 0; r < 4; ++r) {
        int idx = r * 512 + tid;            // ushort8 index
        int c = idx >> 5, d0 = (idx & 31) << 3;
        ulonglong2 t16 = *(const ulonglong2*)&kg[base + c * 256 + d0];
        *(ulonglong2*)&kLs[c * 256 + (d0 ^ ((c & 7) << 3))] = t16;
    }
    if (tid < 64) betaL[tid] = betaG[(size_t)bh * 4096 + (n << 6) + tid];
    __syncthreads();

    // ---- A = strict_tril(beta * (k k^T)) via MFMA over 8 waves:
    // wave wv: row-block rb = wv>>1, col-pair cp = wv&1 (cols cp*32..cp*32+31)
    {
        const int rb = wv >> 1, cp = wv & 1;
        const int arow = (rb << 4) + l15;
        const int kc = l4 << 3;
        f32x4v accA[2] = {vz, vz};
#pragma unroll
        for (int ks = 0; ks < 8; ++ks) {
            const int dbase = (ks << 5) + kc;
            bfv8 afr = *(const bfv8*)&kLs[arow * 256 + (dbase ^ ((arow & 7) << 3))];
#pragma unroll
            for (int et = 0; et < 2; ++et) {
                const int brow = ((cp * 2 + et) << 4) + l15;
                bfv8 bfr = *(const bfv8*)&kLs[brow * 256 + (dbase ^ ((brow & 7) << 3))];
                accA[et] = __builtin_amdgcn_mfma_f32_16x16x32_bf16(afr, bfr, accA[et], 0, 0, 0);
            }
        }
        // C/D: row(c) = rb*16 + l4*4 + j, col(e) = (cp*2+et)*16 + l15
#pragma unroll
        for (int j = 0; j < 4; ++j) {
            const int c = (rb << 4) + (l4 << 2) + j;
            const float bc = betaL[c];
#pragma unroll
            for (int et = 0; et < 2; ++et) {
                const int e = ((cp * 2 + et) << 4) + l15;
                Abuf[c * AST + e] = (e < c) ? accA[et][j] * bc : 0.f;
            }
        }
    }
    __syncthreads();

    // ---- CONCURRENT solves: tid<256 solve (I+A)u = beta*v for column tid,
    //      tid>=256 solve (I+A)w = beta*k for column tid-256.
    const int half = tid >> 8;          // 0 = u, 1 = w
    const int ts = tid & 255;           // column index
    float st[64];
    float km = 0.f;
    if (half == 0) {
#pragma unroll
        for (int c = 0; c < 64; ++c)
            st[c] = betaL[c] * b2f(vG[base + c * 256 + ts]);
    } else {
#pragma unroll
        for (int c = 0; c < 64; ++c) {
            float kv = bu2f(kLs[c * 256 + (ts ^ ((c & 7) << 3))]);
            km += kv;
            st[c] = betaL[c] * kv;
        }
    }
#pragma unroll
    for (int c = 1; c < 64; ++c) {
        float s = 0.f;
        const int G = (c + 3) >> 2;
#pragma unroll
        for (int g = 0; g < G; ++g) {
            float4 a4 = *(const float4*)&Abuf[c * AST + (g << 2)];
            s += a4.x * st[(g << 2) + 0] + a4.y * st[(g << 2) + 1]
               + a4.z * st[(g << 2) + 2] + a4.w * st[(g << 2) + 3];
        }
        st[c] -= s;
    }

    // post-solve: u-half writes u + flux partials (incl. kprojG reads);
    // w-half publishes km.  wOut (aliases kprojG) written after the barrier.
    if (half == 0) {
        float um = 0.f, accv = 0.f;
#pragma unroll
        for (int c = 0; c < 64; ++c) {
            uOut[base + c * 256 + ts] = __float2bfloat16(st[c]);
            um += st[c];
            accv += b2f(kprojG[base + c * 256 + ts]) * st[c];
        }
        fluxL[256 + ts] = um * (1.f / 64.f);
        redL[ts] = accv;
    } else {
        fluxL[ts] = km * (1.f / 64.f);
    }
    __syncthreads();   // orders u-half's kproj reads before w-half's wOut writes
    if (half == 1) {
#pragma unroll
        for (int c = 0; c < 64; ++c)
            wOut[base + c * 256 + ts] = __float2bfloat16(st[c]);
    }
    // accv reduction over redL[0..255]
    for (int s2 = 128; s2 > 0; s2 >>= 1) {
        if (tid < s2) redL[tid] += redL[tid + s2];
        __syncthreads();
    }
    if (tid == 0) fluxL[512] = redL[0] * (1.f / 64.f) / tempG[h];
    __syncthreads();
    // flux MLP, layer 1 split 4-way across 512 threads
    {
        const int g = tid >> 7, j = tid & 127;
        const int i0 = g << 7;
        const int i1 = (g == 3) ? 513 : (i0 + 128);
        float a = 0.f;
        for (int i2 = i0; i2 < i1; ++i2) a += fluxL[i2] * fw1[i2 * 128 + j];
        redL[tid] = a;
    }
    __syncthreads();
    if (tid < 128) {
        float a = fb1[tid] + redL[tid] + redL[128 + tid] + redL[256 + tid] + redL[384 + tid];
        a *= sigmoidf_(a);
        fluxL[520 + tid] = a;
    }
    __syncthreads();
    if (tid < 64) {
        float p = fluxL[520 + tid] * fw2[tid] + fluxL[520 + 64 + tid] * fw2[64 + tid];
#pragma unroll
        for (int off = 32; off > 0; off >>= 1) p += __shfl_xor(p, off);
        if (tid == 0) {
            float ps = sigmoidf_(p + fb2[0]);
            psiOut[chunk] = fminf(0.99f, fmaxf(0.01f, ps));
        }
    }

    // ---- attn = tril(q k^T) via MFMA over 8 waves, q in 32-row halves ----
    u16t* qLs = (u16t*)Abuf;   // [32][256] swizzled, 16 KB
    const size_t abase = (size_t)chunk << 12;
    const int ct2 = wv >> 2, eq = wv & 3;   // wave: 16-row block x 16-col block
    const int qrow = (ct2 << 4) + l15;
    const int kc = l4 << 3;
    for (int hh = 0; hh < 2; ++hh) {
        __syncthreads();   // Abuf (or prior qLs) reads complete
        // stage q half: 2 rounds x 16B per thread (512 threads)
#pragma unroll
        for (int r = 0; r < 2; ++r) {
            int idx = r * 512 + tid;
            int rr = idx >> 5, d0 = (idx & 31) << 3;
            ulonglong2 t16 = *(const ulonglong2*)&qg[base + (size_t)((hh << 5) + rr) * 256 + d0];
            *(ulonglong2*)&qLs[rr * 256 + (d0 ^ ((rr & 7) << 3))] = t16;
        }
        __syncthreads();
        f32x4v accQ = vz;
#pragma unroll
        for (int ks = 0; ks < 8; ++ks) {
            const int dbase = (ks << 5) + kc;
            bfv8 qfr = *(const bfv8*)&qLs[qrow * 256 + (dbase ^ ((qrow & 7) << 3))];
            const int brow = (eq << 4) + l15;
            bfv8 bfr = *(const bfv8*)&kLs[brow * 256 + (dbase ^ ((brow & 7) << 3))];
            accQ = __builtin_amdgcn_mfma_f32_16x16x32_bf16(qfr, bfr, accQ, 0, 0, 0);
        }
#pragma unroll
        for (int j = 0; j < 4; ++j) {
            const int c = (hh << 5) + (ct2 << 4) + (l4 << 2) + j;
            const int e = (eq << 4) + l15;
            attnOut[abase + c * 64 + e] = __float2bfloat16((e <= c) ? accQ[j] : 0.f);
        }
    }
}

// ---------------------------------------------------------------------------
// In-place per-chunk transpose of k: [bh][n][64 c][256 d] -> [bh][n][256 d][64 c]
// (k is only consumed by scan_kernel after this point)
// ---------------------------------------------------------------------------
#define KTS 260
__global__ __launch_bounds__(256)
void ktr_kernel(bf16* kG)
{
    __shared__ u16t tile[64 * KTS];   // 33,280 B (pad 260 breaks stride-1024 banks)
    const size_t base = (size_t)blockIdx.x << 14;   // chunk * 16384 elems
    const int tid = threadIdx.x;
    u16t* kg = (u16t*)kG;
#pragma unroll
    for (int r = 0; r < 16; ++r) {
        int e4 = r * 256 + tid;
        int c = e4 >> 6, dd = (e4 & 63) << 2;
        ushort4 t4 = *(const ushort4*)&kg[base + c * 256 + dd];
        *(ushort4*)&tile[c * KTS + dd] = t4;
    }
    __syncthreads();
#pragma unroll
    for (int r = 0; r < 16; ++r) {
        int e4 = r * 256 + tid;
        int d = e4 >> 4, cc = (e4 & 15) << 2;
        ushort4 o4;
        o4.x = tile[(cc + 0) * KTS + d];
        o4.y = tile[(cc + 1) * KTS + d];
        o4.z = tile[(cc + 2) * KTS + d];
        o4.w = tile[(cc + 3) * KTS + d];
        *(ushort4*)&kg[base + d * 64 + cc] = o4;
    }
}

// ---------------------------------------------------------------------------
// MFMA scan over 64 chunks. One block per (b,h,vslab16) = 256 blocks, 4 waves.
// State Sf/Ss in registers in the dS^T C/D layout:
//   lane: v = (l>>4)*4 + reg, d = (4*wv + t)*16 + (l&15)   (t = 0..3)
// Per chunk: 2 barriers. A-frags (w,q,attn) + B-frags (kT) loaded global->reg
// directly (per-lane 16B). Ssum^T and u_i^T redistributed through swizzled LDS.
// swz: elem col ^ ((row & 7) << 3)  -- 8-group XOR, b128-read safe.
// XCD-aware bh mapping: bh = ((bidx&7)<<1)|(bidx>>7), vb = (bidx>>3)&15 --
// with round-robin blockIdx->XCD dispatch this co-locates all 16 v-slab
// blocks of a bh on ONE XCD, so the shared w/q/kT/attn panels (~104KB/chunk)
// are fetched from HBM once and served from that XCD's L2 thereafter.
// Bijective permutation -> correctness-neutral.
// ---------------------------------------------------------------------------
__global__ __launch_bounds__(256, 1)
void scan_kernel(const bf16* __restrict__ qG, const bf16* __restrict__ kTG,
                 const bf16* __restrict__ wG, const bf16* __restrict__ uG,
                 const bf16* __restrict__ attnG, const float* __restrict__ psiG,
                 const float* __restrict__ lamF, const float* __restrict__ lamS,
                 bf16* __restrict__ oG)
{
    __shared__ __align__(16) u16t ssumT[16 * 256];  // [v][swz(v,d)]  8 KB
    __shared__ __align__(16) u16t uiT[16 * 64];     // [v][swz(v,c)]  2 KB

    const int bidx = blockIdx.x;
    const int bh = ((bidx & 7) << 1) | (bidx >> 7);
    const int vb = (bidx >> 3) & 15;
    const int h = bh & 3;
    const int v0 = vb << 4;
    const int tid = threadIdx.x;
    const int wv = tid >> 6, l = tid & 63;
    const int l15 = l & 15, l4 = l >> 4;
    const float lf = lamF[h], ls = lamS[h];

    const int cA   = (wv << 4) + l15;        // A-operand row (c) for w,q,attn
    const int cO   = (wv << 4) + (l4 << 2);  // C/D output row base (c)
    const int kcol = l4 << 3;                // k-offset within a 32-step
    const int sw15 = (l15 & 7) << 3;         // swizzle term for row l15

    const f32x4v vzero = {0.f, 0.f, 0.f, 0.f};
    f32x4v Sf[4], Ss[4];
#pragma unroll
    for (int t = 0; t < 4; ++t) { Sf[t] = vzero; Ss[t] = vzero; }

    const size_t bhbase = (size_t)bh * 4096 * 256;

    for (int n = 0; n < 64; ++n) {
        const size_t base = bhbase + ((size_t)n << 14);
        const size_t ab = (size_t)((bh << 6) + n) << 12;
        const float p = psiG[(bh << 6) + n];

        // ---- phase A: write Ssum^T (pre-update state); issue global loads ----
#pragma unroll
        for (int t = 0; t < 4; ++t) {
            const int d = (((wv << 2) + t) << 4) + l15;
            f32x4v sv = Sf[t] + Ss[t];
#pragma unroll
            for (int j = 0; j < 4; ++j) {
                const int v = (l4 << 2) + j;
                ssumT[v * 256 + (d ^ ((v & 7) << 3))] = f2bu(sv[j]);
            }
        }
        bfv8 wA[8], qA[8], aA[2], kB[4][2];
#pragma unroll
        for (int ks = 0; ks < 8; ++ks) {
            wA[ks] = *(const bfv8*)&wG[base + (size_t)cA * 256 + (ks << 5) + kcol];
            qA[ks] = *(const bfv8*)&qG[base + (size_t)cA * 256 + (ks << 5) + kcol];
        }
#pragma unroll
        for (int ks = 0; ks < 2; ++ks)
            aA[ks] = *(const bfv8*)&attnG[ab + cA * 64 + (ks << 5) + kcol];
#pragma unroll
        for (int t = 0; t < 4; ++t) {
            const int d = (((wv << 2) + t) << 4) + l15;
            kB[t][0] = *(const bfv8*)&kTG[base + d * 64 + kcol];
            kB[t][1] = *(const bfv8*)&kTG[base + d * 64 + 32 + kcol];
        }
        float u4[4];
#pragma unroll
        for (int j = 0; j < 4; ++j)
            u4[j] = b2f(uG[base + (size_t)(cO + j) * 256 + v0 + l15]);
        __syncthreads();   // Ssum^T visible; staged loads drained

        // ---- phase B: T = w @ Ssum ; u_i = u - T ; write u_i^T ----
        bfv8 sB[8];
#pragma unroll
        for (int ks = 0; ks < 8; ++ks)
            sB[ks] = *(const bfv8*)&ssumT[l15 * 256 + (((ks << 5) + kcol) ^ sw15)];
        f32x4v T = vzero;
#pragma unroll
        for (int ks = 0; ks < 8; ++ks)
            T = __builtin_amdgcn_mfma_f32_16x16x32_bf16(wA[ks], sB[ks], T, 0, 0, 0);
        {
            ushort4 uw;
            uw.x = f2bu(u4[0] - T[0]); uw.y = f2bu(u4[1] - T[1]);
            uw.z = f2bu(u4[2] - T[2]); uw.w = f2bu(u4[3] - T[3]);
            *(ushort4*)&uiT[l15 * 64 + (cO ^ sw15)] = uw;
        }
        __syncthreads();   // u_i^T visible (Ssum^T reads all done)

        // ---- phase C: o = q@Ssum + attn@u_i ; dS^T = u_i^T @ k ; update ----
        bfv8 uT[2];
        uT[0] = *(const bfv8*)&uiT[l15 * 64 + (kcol ^ sw15)];
        uT[1] = *(const bfv8*)&uiT[l15 * 64 + ((32 + kcol) ^ sw15)];
        f32x4v oa = vzero;
        oa = __builtin_amdgcn_mfma_f32_16x16x32_bf16(aA[0], uT[0], oa, 0, 0, 0);
        oa = __builtin_amdgcn_mfma_f32_16x16x32_bf16(aA[1], uT[1], oa, 0, 0, 0);
#pragma unroll
        for (int ks = 0; ks < 8; ++ks)
            oa = __builtin_amdgcn_mfma_f32_16x16x32_bf16(qA[ks], sB[ks], oa, 0, 0, 0);
#pragma unroll
        for (int j = 0; j < 4; ++j)
            oG[base + (size_t)(cO + j) * 256 + v0 + l15] = __float2bfloat16(oa[j]);
        const float pn = 1.f - p;
#pragma unroll
        for (int t = 0; t < 4; ++t) {
            f32x4v ds = vzero;
            ds = __builtin_amdgcn_mfma_f32_16x16x32_bf16(uT[0], kB[t][0], ds, 0, 0, 0);
            ds = __builtin_amdgcn_mfma_f32_16x16x32_bf16(uT[1], kB[t][1], ds, 0, 0, 0);
            Sf[t] = lf * Sf[t] + p  * ds;
            Ss[t] = ls * Ss[t] + pn * ds;
        }
        // no barrier needed: next phase-A Ssum^T write is safe after this
        // wave's bar2 (all waves' Ssum^T reads completed in phase B)
    }
}

// ---------------------------------------------------------------------------
// Final RMSNorm * rms_w * sigmoid(g): chunked o -> natural (B,L,D) bf16
// ---------------------------------------------------------------------------
__global__ __launch_bounds__(256)
void fnorm_kernel(const bf16* __restrict__ oS, const bf16* __restrict__ xg,
                  const float* __restrict__ rmsw, bf16* __restrict__ outn)
{
    const int bt = blockIdx.x;
    const int b = bt >> 12, t = bt & 4095;
    const int tid = threadIdx.x;
    const int h = tid >> 6, lane = tid & 63;
    const int i0 = lane << 2;
    float4 o4 = ld4(&oS[(((size_t)((b << 2) + h)) * 4096 + t) * 256 + i0]);
    float ss = o4.x * o4.x + o4.y * o4.y + o4.z * o4.z + o4.w * o4.w;
#pragma unroll
    for (int off = 32; off > 0; off >>= 1) ss += __shfl_xor(ss, off);
    float r = rsqrtf(ss * (1.f / 256.f) + 1e-5f);
    float4 g4 = ld4(&xg[(size_t)bt * 1024 + (h << 8) + i0]);
    float4 w4 = *(const float4*)&rmsw[i0];
    st4(&outn[(size_t)bt * 1024 + (h << 8) + i0],
        o4.x * r * w4.x * sigmoidf_(g4.x),
        o4.y * r * w4.y * sigmoidf_(g4.y),
        o4.z * r * w4.z * sigmoidf_(g4.z),
        o4.w * r * w4.w * sigmoidf_(g4.w));
}

// ---------------------------------------------------------------------------
extern "C" void kernel_launch(void* const* d_in, const int* in_sizes, int n_in,
                              void* d_out, int out_size, void* d_ws, size_t ws_size,
                              hipStream_t stream)
{
    const float* x    = (const float*)d_in[0];
    const float* Wq   = (const float*)d_in[1];
    const float* Wk   = (const float*)d_in[2];
    const float* Wv   = (const float*)d_in[3];
    const float* Wb   = (const float*)d_in[4];
    const float* Wg   = (const float*)d_in[5];
    const float* Wo   = (const float*)d_in[6];
    const float* cq   = (const float*)d_in[7];
    const float* ck   = (const float*)d_in[8];
    const float* cv   = (const float*)d_in[9];
    const float* Wbil = (const float*)d_in[10];
    const float* temp = (const float*)d_in[11];
    const float* fw1  = (const float*)d_in[12];
    const float* fb1  = (const float*)d_in[13];
    const float* fw2  = (const float*)d_in[14];
    const float* fb2  = (const float*)d_in[15];
    const float* rmsw = (const float*)d_in[16];
    const float* lamF = (const float*)d_in[17];
    const float* lamS = (const float*)d_in[18];
    float* out = (float*)d_out;   // fp32 output, per reference dtype

    const size_t SZ = 16777216ull;             // elems per (B,H,L,DK) slab
    bf16* bws = (bf16*)d_ws;
    bf16* S0 = bws;                            // proj scratch -> g
    bf16* S1 = bws + SZ;                       // q -> onorm
    bf16* S2 = bws + 2 * SZ;                   // k (-> kT in place)
    bf16* S3 = bws + 3 * SZ;                   // v -> o
    bf16* S4 = bws + 4 * SZ;                   // kproj -> w
    bf16* S5 = bws + 5 * SZ;                   // x(bf16) -> u
    bf16* attnB = bws + 6 * SZ;                // 4,194,304 elems (8MB)
    float* p_beta = (float*)(bws + 6 * SZ + 4194304);  // 65,536 fp32
    float* p_psi  = p_beta + 65536;            // 1,024 fp32
    // total ~200.3 MB (unchanged)

    // transposed-bf16 weights live in attnB until chunk_kernel overwrites it
    bf16* Wqt = attnB;
    bf16* Wkt = attnB + 1048576;
    bf16* Wvt = attnB + 2097152;
    bf16* Wgt = attnB + 3145728;

    castx_kernel<<<8192, 256, 0, stream>>>(x, S5);
    castT_kernel<<<dim3(32, 32), 256, 0, stream>>>(Wq, Wqt);
    castT_kernel<<<dim3(32, 32), 256, 0, stream>>>(Wk, Wkt);
    castT_kernel<<<dim3(32, 32), 256, 0, stream>>>(Wv, Wvt);
    castT_kernel<<<dim3(32, 32), 256, 0, stream>>>(Wg, Wgt);

    dim3 gM(8, 128);   // (N/128, M/128)
    mfma_gemm<bf16><<<gM, 256, 0, stream>>>(S5, Wqt, S0, 16384, 1024, 1024, 0, 0, 0, 0);
    conv_kernel<<<16384, 256, 0, stream>>>(S0, cq, S1, 1);
    mfma_gemm<bf16><<<gM, 256, 0, stream>>>(S5, Wkt, S0, 16384, 1024, 1024, 0, 0, 0, 0);
    conv_kernel<<<16384, 256, 0, stream>>>(S0, ck, S2, 1);
    mfma_gemm<bf16><<<gM, 256, 0, stream>>>(S5, Wvt, S0, 16384, 1024, 1024, 0, 0, 0, 0);
    conv_kernel<<<16384, 256, 0, stream>>>(S0, cv, S3, 0);
    mfma_gemm<bf16><<<gM, 256, 0, stream>>>(S5, Wgt, S0, 16384, 1024, 1024, 0, 0, 0, 0);
    beta_kernel<<<16384, 256, 0, stream>>>(x, Wb, p_beta);

    // Wbil -> per-head transposed bf16 (reuse attnB scratch; all Wqt..Wgt
    // reads are complete after the last mfma_gemm above)
    bf16* Wbilt = attnB;
    castTb_kernel<<<dim3(8, 8, 4), 256, 0, stream>>>(Wbil, Wbilt);
    // kproj = k @ Wbil[h] on MFMA: batched z=16, M=4096, N=256, K=256
    mfma_gemm<bf16><<<dim3(2, 32, 16), 256, 0, stream>>>(
        S2, Wbilt, S4, 4096, 256, 256, 1048576ull, 65536ull, 1048576ull, 3);
    chunk_kernel<<<1024, 512, 0, stream>>>(
        S2, S3, S1, p_beta, S4, fw1, fb1, fw2, fb2, temp,
        S5 /*u*/, S4 /*w*/, attnB, p_psi);
    ktr_kernel<<<1024, 256, 0, stream>>>(S2);    // k -> kT in place
    scan_kernel<<<256, 256, 0, stream>>>(
        S1, S2, S4, S5, attnB, p_psi, lamF, lamS, S3 /*o*/);
    // attnB free after scan: reuse for transposed-bf16 Wo
    castT_kernel<<<dim3(32, 32), 256, 0, stream>>>(Wo, attnB);
    fnorm_kernel<<<16384, 256, 0, stream>>>(S3, S0, rmsw, S1);
    mfma_gemm<float><<<gM, 256, 0, stream>>>(S1, attnB, out, 16384, 1024, 1024, 0, 0, 0, 0);
}

// Round 11
// 1010.151 us; speedup vs baseline: 1.0115x; 1.0052x over previous
//
#include <hip/hip_runtime.h>
#include <hip/hip_bf16.h>
#include <type_traits>
#include <stdint.h>

typedef __hip_bfloat16 bf16;
typedef unsigned short u16t;

// B=4, L=4096, D=1024, H=4, DK=256, C=64, NC=64, KS=4
// Harness dtypes: ALL inputs fp32 (per reference setup_inputs), output fp32.
// Internal workspace intermediates: bf16 (2% absmax threshold gives headroom).

__device__ __forceinline__ float sigmoidf_(float x) { return 1.0f / (1.0f + __expf(-x)); }

__device__ __forceinline__ float bu2f(unsigned short u) {
    return __uint_as_float(((unsigned)u) << 16);
}
__device__ __forceinline__ float2 bu2f2(const unsigned short* p) {
    ushort2 t = *(const ushort2*)p;
    float2 r; r.x = bu2f(t.x); r.y = bu2f(t.y); return r;
}
__device__ __forceinline__ float4 ld4(const float* p) { return *(const float4*)p; }
__device__ __forceinline__ float4 ld4(const bf16* p) {
    ushort4 u = *(const ushort4*)p;
    float4 r;
    r.x = bu2f(u.x); r.y = bu2f(u.y); r.z = bu2f(u.z); r.w = bu2f(u.w);
    return r;
}
__device__ __forceinline__ unsigned short f2bu(float x) {
    bf16 h = __float2bfloat16(x);
    return *reinterpret_cast<unsigned short*>(&h);
}
__device__ __forceinline__ void st4(bf16* p, float a, float b, float c, float d) {
    ushort4 u = { f2bu(a), f2bu(b), f2bu(c), f2bu(d) };
    *(ushort4*)p = u;
}
__device__ __forceinline__ float b2f(bf16 h) { return __bfloat162float(h); }

// ---------------------------------------------------------------------------
// MFMA GEMM: C[M,N] = A[M,K] @ B[K,N] where Bt = B^T stored [N][K], bf16 in,
// fp32 accumulate.  128x128 tile, 256 threads (4 waves, 2x2), BK=32,
// global_load_lds width-16 staging, 16x16x32 bf16 MFMA, 4x4 frags per wave.
// Optional batching via blockIdx.z strides.  XCD-aware block swizzle (requires
// gridDim.x*gridDim.y % 8 == 0, true for all call sites: 1024 and 64).
// ---------------------------------------------------------------------------
typedef __bf16 bfv8 __attribute__((ext_vector_type(8)));
typedef float f32x4v __attribute__((ext_vector_type(4)));

// canonical addrspacecast form (compiler lowers generic->AS3 itself)
__device__ __forceinline__ void gl_lds16(const bf16* g, bf16* l) {
    __builtin_amdgcn_global_load_lds(
        (const __attribute__((address_space(1))) unsigned int*)g,
        (__attribute__((address_space(3))) unsigned int*)l,
        16, 0, 0);
}

template <typename OutT>
__global__ __launch_bounds__(256)
void mfma_gemm(const bf16* __restrict__ A, const bf16* __restrict__ Bt,
               OutT* __restrict__ Cm, int M, int N, int K,
               size_t aStride, size_t bStride, size_t cStride, int hMask)
{
    __shared__ __align__(16) bf16 As[4096];   // [128 rows][32 k] linear
    __shared__ __align__(16) bf16 Bs[4096];   // [128 n-rows][32 k] linear (B^T)
    const int z = blockIdx.z;
    A  += (size_t)z * aStride;
    Bt += (size_t)(z & hMask) * bStride;
    Cm += (size_t)z * cStride;
    const int tid = threadIdx.x;
    const int wid = tid >> 6, lane = tid & 63;
    // XCD swizzle: give each XCD a contiguous chunk of the original bid order
    const int nwg = gridDim.x * gridDim.y;
    int bid = blockIdx.y * gridDim.x + blockIdx.x;
    bid = (bid & 7) * (nwg >> 3) + (bid >> 3);
    const int bx = bid % gridDim.x, by = bid / gridDim.x;
    const int m0 = by << 7, n0 = bx << 7;
    const int wr = wid >> 1, wc = wid & 1;    // wave 2x2 over the 128x128 tile

    const int srow = tid >> 2;                // 0..63
    const int scol = (tid & 3) << 3;          // 0,8,16,24
    const bf16* agp = A  + (size_t)(m0 + srow) * K + scol;
    const bf16* bgp = Bt + (size_t)(n0 + srow) * K + scol;
    const size_t rowskip = (size_t)64 * K;
    bf16* al0 = As + wid * 512;
    bf16* al1 = As + 2048 + wid * 512;
    bf16* bl0 = Bs + wid * 512;
    bf16* bl1 = Bs + 2048 + wid * 512;

    // fragment LDS offsets: A[row = l&15][k = (l>>4)*8 + j]
    const int aoff = (wr * 64 + (lane & 15)) * 32 + ((lane >> 4) << 3);
    const int boff = (wc * 64 + (lane & 15)) * 32 + ((lane >> 4) << 3);

    const f32x4v vzero = {0.f, 0.f, 0.f, 0.f};
    f32x4v acc[4][4];
#pragma unroll
    for (int i = 0; i < 4; ++i)
#pragma unroll
        for (int j = 0; j < 4; ++j) acc[i][j] = vzero;

    for (int k0 = 0; k0 < K; k0 += 32) {
        gl_lds16(agp,           al0);
        gl_lds16(agp + rowskip, al1);
        gl_lds16(bgp,           bl0);
        gl_lds16(bgp + rowskip, bl1);
        agp += 32; bgp += 32;
        __syncthreads();
        bfv8 af[4], bfr[4];
#pragma unroll
        for (int i = 0; i < 4; ++i) {
            af[i]  = *(const bfv8*)(As + aoff + i * 16 * 32);
            bfr[i] = *(const bfv8*)(Bs + boff + i * 16 * 32);
        }
#pragma unroll
        for (int mi = 0; mi < 4; ++mi)
#pragma unroll
            for (int ni = 0; ni < 4; ++ni)
                acc[mi][ni] = __builtin_amdgcn_mfma_f32_16x16x32_bf16(
                    af[mi], bfr[ni], acc[mi][ni], 0, 0, 0);
        __syncthreads();
    }

    const int crow = (lane >> 4) << 2;
    const int ccol = lane & 15;
#pragma unroll
    for (int mi = 0; mi < 4; ++mi)
#pragma unroll
        for (int ni = 0; ni < 4; ++ni)
#pragma unroll
            for (int j = 0; j < 4; ++j) {
                size_t r = (size_t)(m0 + wr * 64 + mi * 16 + crow + j) * N
                         + (n0 + wc * 64 + ni * 16 + ccol);
                if constexpr (std::is_same<OutT, float>::value)
                    Cm[r] = acc[mi][ni][j];
                else
                    Cm[r] = __float2bfloat16(acc[mi][ni][j]);
            }
}

// fp32 -> bf16 elementwise cast (x), 8 elems/thread
__global__ __launch_bounds__(256)
void castx_kernel(const float* __restrict__ x, bf16* __restrict__ xb)
{
    size_t i = ((size_t)blockIdx.x * 256 + threadIdx.x) * 8;
    float4 a = ld4(&x[i]);
    float4 b = ld4(&x[i + 4]);
    st4(xb + i,     a.x, a.y, a.z, a.w);
    st4(xb + i + 4, b.x, b.y, b.z, b.w);
}

// fp32 [1024][1024] -> bf16 transposed [1024][1024]
__global__ __launch_bounds__(256)
void castT_kernel(const float* __restrict__ W, bf16* __restrict__ Wt)
{
    __shared__ float tile[32][33];
    const int tid = threadIdx.x;
    const int tx = tid & 31, ty = tid >> 5;   // 32 x 8
    const int c0 = blockIdx.x << 5, r0 = blockIdx.y << 5;
#pragma unroll
    for (int r = 0; r < 4; ++r)
        tile[ty + r * 8][tx] = W[(size_t)(r0 + ty + r * 8) * 1024 + c0 + tx];
    __syncthreads();
#pragma unroll
    for (int r = 0; r < 4; ++r)
        Wt[(size_t)(c0 + ty + r * 8) * 1024 + r0 + tx] =
            __float2bfloat16(tile[tx][ty + r * 8]);
}

// fp32 [4][256][256] -> bf16 per-head transposed [4][256][256]
__global__ __launch_bounds__(256)
void castTb_kernel(const float* __restrict__ W, bf16* __restrict__ Wt)
{
    __shared__ float tile[32][33];
    const int tid = threadIdx.x;
    const int tx = tid & 31, ty = tid >> 5;   // 32 x 8
    const int c0 = blockIdx.x << 5, r0 = blockIdx.y << 5;
    const size_t hb = (size_t)blockIdx.z << 16;
#pragma unroll
    for (int r = 0; r < 4; ++r)
        tile[ty + r * 8][tx] = W[hb + (size_t)(r0 + ty + r * 8) * 256 + c0 + tx];
    __syncthreads();
#pragma unroll
    for (int r = 0; r < 4; ++r)
        Wt[hb + (size_t)(c0 + ty + r * 8) * 256 + r0 + tx] =
            __float2bfloat16(tile[tx][ty + r * 8]);
}

// ---------------------------------------------------------------------------
// Depthwise conv (taps x[t-2+j], j=0..3) + SiLU + optional per-head l2norm.
// ---------------------------------------------------------------------------
__global__ __launch_bounds__(256)
void conv_kernel(const bf16* __restrict__ xin, const float* __restrict__ cw,
                 bf16* __restrict__ outc, int doNorm)
{
    const int bt = blockIdx.x;
    const int b = bt >> 12, t = bt & 4095;
    const int tid = threadIdx.x;
    const int h = tid >> 6, lane = tid & 63;
    const int i0 = lane << 2;
    const int d = (h << 8) + i0;
    float w0[4], w1[4], w2[4], w3[4];
    {
        float4 c0 = *(const float4*)&cw[(d + 0) * 4];
        float4 c1 = *(const float4*)&cw[(d + 1) * 4];
        float4 c2 = *(const float4*)&cw[(d + 2) * 4];
        float4 c3 = *(const float4*)&cw[(d + 3) * 4];
        w0[0] = c0.x; w0[1] = c0.y; w0[2] = c0.z; w0[3] = c0.w;
        w1[0] = c1.x; w1[1] = c1.y; w1[2] = c1.z; w1[3] = c1.w;
        w2[0] = c2.x; w2[1] = c2.y; w2[2] = c2.z; w2[3] = c2.w;
        w3[0] = c3.x; w3[1] = c3.y; w3[2] = c3.z; w3[3] = c3.w;
    }
    float acc[4] = {0.f, 0.f, 0.f, 0.f};
#pragma unroll
    for (int jj = 0; jj < 4; ++jj) {
        int tt = t - 2 + jj;
        if (tt >= 0 && tt < 4096) {
            float4 xr = ld4(&xin[((size_t)(b << 12) + tt) * 1024 + d]);
            acc[0] += xr.x * w0[jj];
            acc[1] += xr.y * w1[jj];
            acc[2] += xr.z * w2[jj];
            acc[3] += xr.w * w3[jj];
        }
    }
#pragma unroll
    for (int j = 0; j < 4; ++j) acc[j] *= sigmoidf_(acc[j]);
    if (doNorm) {
        float ss = acc[0]*acc[0] + acc[1]*acc[1] + acc[2]*acc[2] + acc[3]*acc[3];
#pragma unroll
        for (int off = 32; off > 0; off >>= 1) ss += __shfl_xor(ss, off);
        float r = rsqrtf(ss + 1e-6f);
        acc[0] *= r; acc[1] *= r; acc[2] *= r; acc[3] *= r;
    }
    st4(&outc[(((size_t)((b << 2) + h)) * 4096 + t) * 256 + i0],
        acc[0], acc[1], acc[2], acc[3]);
}

// ---------------------------------------------------------------------------
// beta = sigmoid(x @ Wb), stored (B*H, L) fp32.  x is fp32 input.
// ---------------------------------------------------------------------------
__global__ __launch_bounds__(256)
void beta_kernel(const float* __restrict__ x, const float* __restrict__ Wb,
                 float* __restrict__ beta)
{
    const int bt = blockIdx.x;
    const int b = bt >> 12, t = bt & 4095;
    const int tid = threadIdx.x;
    const int wv = tid >> 6;
    __shared__ float redB[4][4];
    float4 xv = *(const float4*)&x[(size_t)bt * 1024 + (tid << 2)];
    float xa[4] = {xv.x, xv.y, xv.z, xv.w};
    float a[4] = {0.f, 0.f, 0.f, 0.f};
#pragma unroll
    for (int j = 0; j < 4; ++j) {
        float4 wr = *(const float4*)&Wb[((tid << 2) + j) * 4];
        a[0] += xa[j] * wr.x; a[1] += xa[j] * wr.y;
        a[2] += xa[j] * wr.z; a[3] += xa[j] * wr.w;
    }
#pragma unroll
    for (int hh = 0; hh < 4; ++hh)
#pragma unroll
        for (int off = 32; off > 0; off >>= 1) a[hh] += __shfl_xor(a[hh], off);
    if ((tid & 63) == 0) {
        redB[wv][0] = a[0]; redB[wv][1] = a[1]; redB[wv][2] = a[2]; redB[wv][3] = a[3];
    }
    __syncthreads();
    if (tid < 4) {
        float s = redB[0][tid] + redB[1][tid] + redB[2][tid] + redB[3][tid];
        beta[((size_t)((b << 2) + tid)) * 4096 + t] = sigmoidf_(s);
    }
}

// ---------------------------------------------------------------------------
// Per-chunk kernel, 512 threads (8 waves). NO __restrict__ (kprojG aliases
// wOut).  A and attn on MFMA (k XOR-swizzled in LDS).  The u and w triangular
// solves run CONCURRENTLY on separate thread halves (tid<256: u, tid>=256: w)
// with one 64-reg state array each -> no spill.
// kprojG/wOut alias is cross-thread: u-half reads kproj BEFORE the barrier,
// w-half writes wOut AFTER it.
// ---------------------------------------------------------------------------
#define AST 68
__global__ __launch_bounds__(512)
void chunk_kernel(const bf16* kG, const bf16* vG,
                  const bf16* qG, const float* betaG,
                  const bf16* kprojG,
                  const float* fw1, const float* fb1,
                  const float* fw2, const float* fb2,
                  const float* tempG,
                  bf16* uOut, bf16* wOut,
                  bf16* attnOut, float* psiOut)
{
    __shared__ __align__(16) u16t kLs[64 * 256];   // 32,768 B, swizzled
    __shared__ __align__(16) float Abuf[64 * AST]; // 17,408 B (reused as q half)
    __shared__ float betaL[64];
    __shared__ float fluxL[648];
    __shared__ float redL[512];

    const int chunk = blockIdx.x;
    const int bh = chunk >> 6;
    const int n  = chunk & 63;
    const int h  = bh & 3;
    const int tid = threadIdx.x;
    const int wv = tid >> 6, l = tid & 63;
    const int l15 = l & 15, l4 = l >> 4;
    const size_t base = ((size_t)bh * 4096 + n * 64) * 256;
    const u16t* kg = (const u16t*)kG;
    const u16t* qg = (const u16t*)qG;
    const f32x4v vz = {0.f, 0.f, 0.f, 0.f};

    // stage k -> LDS swizzled (4 rounds x 16B per thread, 512 threads)
#pragma unroll
    for (int r = 0; r < 4; ++r) {
        int idx = r * 512 + tid;            // ushort8 index
        int c = idx >> 5, d0 = (idx & 31) << 3;
        ulonglong2 t16 = *(const ulonglong2*)&kg[base + c * 256 + d0];
        *(ulonglong2*)&kLs[c * 256 + (d0 ^ ((c & 7) << 3))] = t16;
    }
    if (tid < 64) betaL[tid] = betaG[(size_t)bh * 4096 + (n << 6) + tid];
    __syncthreads();

    // ---- A = strict_tril(beta * (k k^T)) via MFMA over 8 waves:
    // wave wv: row-block rb = wv>>1, col-pair cp = wv&1 (cols cp*32..cp*32+31)
    {
        const int rb = wv >> 1, cp = wv & 1;
        const int arow = (rb << 4) + l15;
        const int kc = l4 << 3;
        f32x4v accA[2] = {vz, vz};
#pragma unroll
        for (int ks = 0; ks < 8; ++ks) {
            const int dbase = (ks << 5) + kc;
            bfv8 afr = *(const bfv8*)&kLs[arow * 256 + (dbase ^ ((arow & 7) << 3))];
#pragma unroll
            for (int et = 0; et < 2; ++et) {
                const int brow = ((cp * 2 + et) << 4) + l15;
                bfv8 bfr = *(const bfv8*)&kLs[brow * 256 + (dbase ^ ((brow & 7) << 3))];
                accA[et] = __builtin_amdgcn_mfma_f32_16x16x32_bf16(afr, bfr, accA[et], 0, 0, 0);
            }
        }
        // C/D: row(c) = rb*16 + l4*4 + j, col(e) = (cp*2+et)*16 + l15
#pragma unroll
        for (int j = 0; j < 4; ++j) {
            const int c = (rb << 4) + (l4 << 2) + j;
            const float bc = betaL[c];
#pragma unroll
            for (int et = 0; et < 2; ++et) {
                const int e = ((cp * 2 + et) << 4) + l15;
                Abuf[c * AST + e] = (e < c) ? accA[et][j] * bc : 0.f;
            }
        }
    }
    __syncthreads();

    // ---- CONCURRENT solves: tid<256 solve (I+A)u = beta*v for column tid,
    //      tid>=256 solve (I+A)w = beta*k for column tid-256.
    const int half = tid >> 8;          // 0 = u, 1 = w
    const int ts = tid & 255;           // column index
    float st[64];
    float km = 0.f;
    if (half == 0) {
#pragma unroll
        for (int c = 0; c < 64; ++c)
            st[c] = betaL[c] * b2f(vG[base + c * 256 + ts]);
    } else {
#pragma unroll
        for (int c = 0; c < 64; ++c) {
            float kv = bu2f(kLs[c * 256 + (ts ^ ((c & 7) << 3))]);
            km += kv;
            st[c] = betaL[c] * kv;
        }
    }
#pragma unroll
    for (int c = 1; c < 64; ++c) {
        float s = 0.f;
        const int G = (c + 3) >> 2;
#pragma unroll
        for (int g = 0; g < G; ++g) {
            float4 a4 = *(const float4*)&Abuf[c * AST + (g << 2)];
            s += a4.x * st[(g << 2) + 0] + a4.y * st[(g << 2) + 1]
               + a4.z * st[(g << 2) + 2] + a4.w * st[(g << 2) + 3];
        }
        st[c] -= s;
    }

    // post-solve: u-half writes u + flux partials (incl. kprojG reads);
    // w-half publishes km.  wOut (aliases kprojG) written after the barrier.
    if (half == 0) {
        float um = 0.f, accv = 0.f;
#pragma unroll
        for (int c = 0; c < 64; ++c) {
            uOut[base + c * 256 + ts] = __float2bfloat16(st[c]);
            um += st[c];
            accv += b2f(kprojG[base + c * 256 + ts]) * st[c];
        }
        fluxL[256 + ts] = um * (1.f / 64.f);
        redL[ts] = accv;
    } else {
        fluxL[ts] = km * (1.f / 64.f);
    }
    __syncthreads();   // orders u-half's kproj reads before w-half's wOut writes
    if (half == 1) {
#pragma unroll
        for (int c = 0; c < 64; ++c)
            wOut[base + c * 256 + ts] = __float2bfloat16(st[c]);
    }
    // accv reduction over redL[0..255]
    for (int s2 = 128; s2 > 0; s2 >>= 1) {
        if (tid < s2) redL[tid] += redL[tid + s2];
        __syncthreads();
    }
    if (tid == 0) fluxL[512] = redL[0] * (1.f / 64.f) / tempG[h];
    __syncthreads();
    // flux MLP, layer 1 split 4-way across 512 threads
    {
        const int g = tid >> 7, j = tid & 127;
        const int i0 = g << 7;
        const int i1 = (g == 3) ? 513 : (i0 + 128);
        float a = 0.f;
        for (int i2 = i0; i2 < i1; ++i2) a += fluxL[i2] * fw1[i2 * 128 + j];
        redL[tid] = a;
    }
    __syncthreads();
    if (tid < 128) {
        float a = fb1[tid] + redL[tid] + redL[128 + tid] + redL[256 + tid] + redL[384 + tid];
        a *= sigmoidf_(a);
        fluxL[520 + tid] = a;
    }
    __syncthreads();
    if (tid < 64) {
        float p = fluxL[520 + tid] * fw2[tid] + fluxL[520 + 64 + tid] * fw2[64 + tid];
#pragma unroll
        for (int off = 32; off > 0; off >>= 1) p += __shfl_xor(p, off);
        if (tid == 0) {
            float ps = sigmoidf_(p + fb2[0]);
            psiOut[chunk] = fminf(0.99f, fmaxf(0.01f, ps));
        }
    }

    // ---- attn = tril(q k^T) via MFMA over 8 waves, q in 32-row halves ----
    u16t* qLs = (u16t*)Abuf;   // [32][256] swizzled, 16 KB
    const size_t abase = (size_t)chunk << 12;
    const int ct2 = wv >> 2, eq = wv & 3;   // wave: 16-row block x 16-col block
    const int qrow = (ct2 << 4) + l15;
    const int kc = l4 << 3;
    for (int hh = 0; hh < 2; ++hh) {
        __syncthreads();   // Abuf (or prior qLs) reads complete
        // stage q half: 2 rounds x 16B per thread (512 threads)
#pragma unroll
        for (int r = 0; r < 2; ++r) {
            int idx = r * 512 + tid;
            int rr = idx >> 5, d0 = (idx & 31) << 3;
            ulonglong2 t16 = *(const ulonglong2*)&qg[base + (size_t)((hh << 5) + rr) * 256 + d0];
            *(ulonglong2*)&qLs[rr * 256 + (d0 ^ ((rr & 7) << 3))] = t16;
        }
        __syncthreads();
        f32x4v accQ = vz;
#pragma unroll
        for (int ks = 0; ks < 8; ++ks) {
            const int dbase = (ks << 5) + kc;
            bfv8 qfr = *(const bfv8*)&qLs[qrow * 256 + (dbase ^ ((qrow & 7) << 3))];
            const int brow = (eq << 4) + l15;
            bfv8 bfr = *(const bfv8*)&kLs[brow * 256 + (dbase ^ ((brow & 7) << 3))];
            accQ = __builtin_amdgcn_mfma_f32_16x16x32_bf16(qfr, bfr, accQ, 0, 0, 0);
        }
#pragma unroll
        for (int j = 0; j < 4; ++j) {
            const int c = (hh << 5) + (ct2 << 4) + (l4 << 2) + j;
            const int e = (eq << 4) + l15;
            attnOut[abase + c * 64 + e] = __float2bfloat16((e <= c) ? accQ[j] : 0.f);
        }
    }
}

// ---------------------------------------------------------------------------
// In-place per-chunk transpose of k: [bh][n][64 c][256 d] -> [bh][n][256 d][64 c]
// (k is only consumed by scan_kernel after this point)
// ---------------------------------------------------------------------------
#define KTS 260
__global__ __launch_bounds__(256)
void ktr_kernel(bf16* kG)
{
    __shared__ u16t tile[64 * KTS];   // 33,280 B (pad 260 breaks stride-1024 banks)
    const size_t base = (size_t)blockIdx.x << 14;   // chunk * 16384 elems
    const int tid = threadIdx.x;
    u16t* kg = (u16t*)kG;
#pragma unroll
    for (int r = 0; r < 16; ++r) {
        int e4 = r * 256 + tid;
        int c = e4 >> 6, dd = (e4 & 63) << 2;
        ushort4 t4 = *(const ushort4*)&kg[base + c * 256 + dd];
        *(ushort4*)&tile[c * KTS + dd] = t4;
    }
    __syncthreads();
#pragma unroll
    for (int r = 0; r < 16; ++r) {
        int e4 = r * 256 + tid;
        int d = e4 >> 4, cc = (e4 & 15) << 2;
        ushort4 o4;
        o4.x = tile[(cc + 0) * KTS + d];
        o4.y = tile[(cc + 1) * KTS + d];
        o4.z = tile[(cc + 2) * KTS + d];
        o4.w = tile[(cc + 3) * KTS + d];
        *(ushort4*)&kg[base + d * 64 + cc] = o4;
    }
}

// ---------------------------------------------------------------------------
// MFMA scan over 64 chunks, SOFTWARE-PIPELINED + XCD bh co-location.
// One block per (b,h,vslab16) = 256 blocks, 4 waves.
// bh = ((bidx&7)<<1)|(bidx>>7), vb = (bidx>>3)&15: co-locates all 16 v-slab
// blocks of one bh on one XCD (round-robin dispatch) -> shared panels L2-hit.
// Load scheduling (every __syncthreads drains vmcnt(0)):
//   - qA/aA/kB: issued at B-interval head -> hidden under phase B (L2 lat).
//   - wA/u4: double-buffered cross-chunk; issued at C-head for chunk n+1 ->
//     hidden under phase C + phase A(n+1).
// Dual accumulators split the 8/10-deep dependent-MFMA chains into 4/5-deep.
// ---------------------------------------------------------------------------
__device__ __forceinline__ void scan_step(
    int nn, bool last,
    bfv8 (&WAc)[8], ushort4& U4c, bfv8 (&WAn)[8], ushort4& U4n,
    f32x4v (&Sf)[4], f32x4v (&Ss)[4],
    const bf16* __restrict__ qG, const bf16* __restrict__ kTG,
    const bf16* __restrict__ wG, const bf16* __restrict__ uG,
    const bf16* __restrict__ attnG, const float* __restrict__ psiG,
    bf16* __restrict__ oG, u16t* ssumT, u16t* uiT,
    size_t bhbase, int bh, int v0, int wv, int l15, int l4,
    int cA, int cO, int kcol, int sw15, float lf, float ls)
{
    const f32x4v vzero = {0.f, 0.f, 0.f, 0.f};
    const size_t base = bhbase + ((size_t)nn << 14);
    const size_t ab = (size_t)((bh << 6) + nn) << 12;
    const float p = psiG[(bh << 6) + nn];

    // ---- phase A: publish Ssum^T (pre-update state) ----
#pragma unroll
    for (int t = 0; t < 4; ++t) {
        const int d = (((wv << 2) + t) << 4) + l15;
        f32x4v sv = Sf[t] + Ss[t];
#pragma unroll
        for (int j = 0; j < 4; ++j) {
            const int v = (l4 << 2) + j;
            ssumT[v * 256 + (d ^ ((v & 7) << 3))] = f2bu(sv[j]);
        }
    }
    __syncthreads();   // drains WAc/U4c (in flight since previous C head)

    // ---- phase B head: issue this chunk's C-phase operands ----
    bfv8 qA[8], aA[2], kB[4][2];
#pragma unroll
    for (int ks = 0; ks < 8; ++ks)
        qA[ks] = *(const bfv8*)&qG[base + (size_t)cA * 256 + (ks << 5) + kcol];
#pragma unroll
    for (int ks = 0; ks < 2; ++ks)
        aA[ks] = *(const bfv8*)&attnG[ab + cA * 64 + (ks << 5) + kcol];
#pragma unroll
    for (int t = 0; t < 4; ++t) {
        const int d = (((wv << 2) + t) << 4) + l15;
        kB[t][0] = *(const bfv8*)&kTG[base + d * 64 + kcol];
        kB[t][1] = *(const bfv8*)&kTG[base + d * 64 + 32 + kcol];
    }

    // ---- phase B: T = w @ Ssum ; u_i = u - T ; write u_i^T ----
    bfv8 sB[8];
#pragma unroll
    for (int ks = 0; ks < 8; ++ks)
        sB[ks] = *(const bfv8*)&ssumT[l15 * 256 + (((ks << 5) + kcol) ^ sw15)];
    f32x4v T1 = vzero, T2 = vzero;
#pragma unroll
    for (int ks = 0; ks < 4; ++ks) {
        T1 = __builtin_amdgcn_mfma_f32_16x16x32_bf16(WAc[ks],     sB[ks],     T1, 0, 0, 0);
        T2 = __builtin_amdgcn_mfma_f32_16x16x32_bf16(WAc[ks + 4], sB[ks + 4], T2, 0, 0, 0);
    }
    f32x4v T = T1 + T2;
    {
        ushort4 uw;
        uw.x = f2bu(bu2f(U4c.x) - T[0]); uw.y = f2bu(bu2f(U4c.y) - T[1]);
        uw.z = f2bu(bu2f(U4c.z) - T[2]); uw.w = f2bu(bu2f(U4c.w) - T[3]);
        *(ushort4*)&uiT[l15 * 64 + (cO ^ sw15)] = uw;
    }
    __syncthreads();   // drains qA/aA/kB (hidden under phase B)

    // ---- phase C head: issue NEXT chunk's wA/u4 (double buffer) ----
    {
        const int np = last ? nn : nn + 1;
        const size_t bn = bhbase + ((size_t)np << 14);
#pragma unroll
        for (int ks = 0; ks < 8; ++ks)
            WAn[ks] = *(const bfv8*)&wG[bn + (size_t)cA * 256 + (ks << 5) + kcol];
        const u16t* ug = (const u16t*)uG;
        U4n.x = ug[bn + (size_t)(cO + 0) * 256 + v0 + l15];
        U4n.y = ug[bn + (size_t)(cO + 1) * 256 + v0 + l15];
        U4n.z = ug[bn + (size_t)(cO + 2) * 256 + v0 + l15];
        U4n.w = ug[bn + (size_t)(cO + 3) * 256 + v0 + l15];
    }

    // ---- phase C: o = q@Ssum + attn@u_i ; dS^T = u_i^T @ k ; update ----
    bfv8 uT[2];
    uT[0] = *(const bfv8*)&uiT[l15 * 64 + (kcol ^ sw15)];
    uT[1] = *(const bfv8*)&uiT[l15 * 64 + ((32 + kcol) ^ sw15)];
    f32x4v oa1 = vzero, oa2 = vzero;
    oa1 = __builtin_amdgcn_mfma_f32_16x16x32_bf16(aA[0], uT[0], oa1, 0, 0, 0);
    oa2 = __builtin_amdgcn_mfma_f32_16x16x32_bf16(aA[1], uT[1], oa2, 0, 0, 0);
#pragma unroll
    for (int ks = 0; ks < 4; ++ks) {
        oa1 = __builtin_amdgcn_mfma_f32_16x16x32_bf16(qA[ks],     sB[ks],     oa1, 0, 0, 0);
        oa2 = __builtin_amdgcn_mfma_f32_16x16x32_bf16(qA[ks + 4], sB[ks + 4], oa2, 0, 0, 0);
    }
    f32x4v oa = oa1 + oa2;
#pragma unroll
    for (int j = 0; j < 4; ++j)
        oG[base + (size_t)(cO + j) * 256 + v0 + l15] = __float2bfloat16(oa[j]);
    const float pn = 1.f - p;
#pragma unroll
    for (int t = 0; t < 4; ++t) {
        f32x4v ds = vzero;
        ds = __builtin_amdgcn_mfma_f32_16x16x32_bf16(uT[0], kB[t][0], ds, 0, 0, 0);
        ds = __builtin_amdgcn_mfma_f32_16x16x32_bf16(uT[1], kB[t][1], ds, 0, 0, 0);
        Sf[t] = lf * Sf[t] + p  * ds;
        Ss[t] = ls * Ss[t] + pn * ds;
    }
    // no barrier at chunk end: next phase-A write is ordered by barrier-B
}

__global__ __launch_bounds__(256, 1)
void scan_kernel(const bf16* __restrict__ qG, const bf16* __restrict__ kTG,
                 const bf16* __restrict__ wG, const bf16* __restrict__ uG,
                 const bf16* __restrict__ attnG, const float* __restrict__ psiG,
                 const float* __restrict__ lamF, const float* __restrict__ lamS,
                 bf16* __restrict__ oG)
{
    __shared__ __align__(16) u16t ssumT[16 * 256];  // [v][swz(v,d)]  8 KB
    __shared__ __align__(16) u16t uiT[16 * 64];     // [v][swz(v,c)]  2 KB

    const int bidx = blockIdx.x;
    const int bh = ((bidx & 7) << 1) | (bidx >> 7);
    const int vb = (bidx >> 3) & 15;
    const int h = bh & 3;
    const int v0 = vb << 4;
    const int tid = threadIdx.x;
    const int wv = tid >> 6, l = tid & 63;
    const int l15 = l & 15, l4 = l >> 4;
    const float lf = lamF[h], ls = lamS[h];

    const int cA   = (wv << 4) + l15;        // A-operand row (c) for w,q,attn
    const int cO   = (wv << 4) + (l4 << 2);  // C/D output row base (c)
    const int kcol = l4 << 3;                // k-offset within a 32-step
    const int sw15 = (l15 & 7) << 3;         // swizzle term for row l15

    const f32x4v vzero = {0.f, 0.f, 0.f, 0.f};
    f32x4v Sf[4], Ss[4];
#pragma unroll
    for (int t = 0; t < 4; ++t) { Sf[t] = vzero; Ss[t] = vzero; }

    const size_t bhbase = (size_t)bh * 4096 * 256;

    // prologue: load chunk 0's wA/u4
    bfv8 wA0[8], wA1[8];
    ushort4 u40, u41;
    {
#pragma unroll
        for (int ks = 0; ks < 8; ++ks)
            wA0[ks] = *(const bfv8*)&wG[bhbase + (size_t)cA * 256 + (ks << 5) + kcol];
        const u16t* ug = (const u16t*)uG;
        u40.x = ug[bhbase + (size_t)(cO + 0) * 256 + v0 + l15];
        u40.y = ug[bhbase + (size_t)(cO + 1) * 256 + v0 + l15];
        u40.z = ug[bhbase + (size_t)(cO + 2) * 256 + v0 + l15];
        u40.w = ug[bhbase + (size_t)(cO + 3) * 256 + v0 + l15];
    }

    for (int n = 0; n < 64; n += 2) {
        scan_step(n,     false,       wA0, u40, wA1, u41, Sf, Ss,
                  qG, kTG, wG, uG, attnG, psiG, oG, ssumT, uiT,
                  bhbase, bh, v0, wv, l15, l4, cA, cO, kcol, sw15, lf, ls);
        scan_step(n + 1, n + 1 == 63, wA1, u41, wA0, u40, Sf, Ss,
                  qG, kTG, wG, uG, attnG, psiG, oG, ssumT, uiT,
                  bhbase, bh, v0, wv, l15, l4, cA, cO, kcol, sw15, lf, ls);
    }
}

// ---------------------------------------------------------------------------
// Final RMSNorm * rms_w * sigmoid(g): chunked o -> natural (B,L,D) bf16
// ---------------------------------------------------------------------------
__global__ __launch_bounds__(256)
void fnorm_kernel(const bf16* __restrict__ oS, const bf16* __restrict__ xg,
                  const float* __restrict__ rmsw, bf16* __restrict__ outn)
{
    const int bt = blockIdx.x;
    const int b = bt >> 12, t = bt & 4095;
    const int tid = threadIdx.x;
    const int h = tid >> 6, lane = tid & 63;
    const int i0 = lane << 2;
    float4 o4 = ld4(&oS[(((size_t)((b << 2) + h)) * 4096 + t) * 256 + i0]);
    float ss = o4.x * o4.x + o4.y * o4.y + o4.z * o4.z + o4.w * o4.w;
#pragma unroll
    for (int off = 32; off > 0; off >>= 1) ss += __shfl_xor(ss, off);
    float r = rsqrtf(ss * (1.f / 256.f) + 1e-5f);
    float4 g4 = ld4(&xg[(size_t)bt * 1024 + (h << 8) + i0]);
    float4 w4 = *(const float4*)&rmsw[i0];
    st4(&outn[(size_t)bt * 1024 + (h << 8) + i0],
        o4.x * r * w4.x * sigmoidf_(g4.x),
        o4.y * r * w4.y * sigmoidf_(g4.y),
        o4.z * r * w4.z * sigmoidf_(g4.z),
        o4.w * r * w4.w * sigmoidf_(g4.w));
}

// ---------------------------------------------------------------------------
extern "C" void kernel_launch(void* const* d_in, const int* in_sizes, int n_in,
                              void* d_out, int out_size, void* d_ws, size_t ws_size,
                              hipStream_t stream)
{
    const float* x    = (const float*)d_in[0];
    const float* Wq   = (const float*)d_in[1];
    const float* Wk   = (const float*)d_in[2];
    const float* Wv   = (const float*)d_in[3];
    const float* Wb   = (const float*)d_in[4];
    const float* Wg   = (const float*)d_in[5];
    const float* Wo   = (const float*)d_in[6];
    const float* cq   = (const float*)d_in[7];
    const float* ck   = (const float*)d_in[8];
    const float* cv   = (const float*)d_in[9];
    const float* Wbil = (const float*)d_in[10];
    const float* temp = (const float*)d_in[11];
    const float* fw1  = (const float*)d_in[12];
    const float* fb1  = (const float*)d_in[13];
    const float* fw2  = (const float*)d_in[14];
    const float* fb2  = (const float*)d_in[15];
    const float* rmsw = (const float*)d_in[16];
    const float* lamF = (const float*)d_in[17];
    const float* lamS = (const float*)d_in[18];
    float* out = (float*)d_out;   // fp32 output, per reference dtype

    const size_t SZ = 16777216ull;             // elems per (B,H,L,DK) slab
    bf16* bws = (bf16*)d_ws;
    bf16* S0 = bws;                            // proj scratch -> g
    bf16* S1 = bws + SZ;                       // q -> onorm
    bf16* S2 = bws + 2 * SZ;                   // k (-> kT in place)
    bf16* S3 = bws + 3 * SZ;                   // v -> o
    bf16* S4 = bws + 4 * SZ;                   // kproj -> w
    bf16* S5 = bws + 5 * SZ;                   // x(bf16) -> u
    bf16* attnB = bws + 6 * SZ;                // 4,194,304 elems (8MB)
    float* p_beta = (float*)(bws + 6 * SZ + 4194304);  // 65,536 fp32
    float* p_psi  = p_beta + 65536;            // 1,024 fp32
    // total ~200.3 MB (unchanged)

    // transposed-bf16 weights live in attnB until chunk_kernel overwrites it
    bf16* Wqt = attnB;
    bf16* Wkt = attnB + 1048576;
    bf16* Wvt = attnB + 2097152;
    bf16* Wgt = attnB + 3145728;

    castx_kernel<<<8192, 256, 0, stream>>>(x, S5);
    castT_kernel<<<dim3(32, 32), 256, 0, stream>>>(Wq, Wqt);
    castT_kernel<<<dim3(32, 32), 256, 0, stream>>>(Wk, Wkt);
    castT_kernel<<<dim3(32, 32), 256, 0, stream>>>(Wv, Wvt);
    castT_kernel<<<dim3(32, 32), 256, 0, stream>>>(Wg, Wgt);

    dim3 gM(8, 128);   // (N/128, M/128)
    mfma_gemm<bf16><<<gM, 256, 0, stream>>>(S5, Wqt, S0, 16384, 1024, 1024, 0, 0, 0, 0);
    conv_kernel<<<16384, 256, 0, stream>>>(S0, cq, S1, 1);
    mfma_gemm<bf16><<<gM, 256, 0, stream>>>(S5, Wkt, S0, 16384, 1024, 1024, 0, 0, 0, 0);
    conv_kernel<<<16384, 256, 0, stream>>>(S0, ck, S2, 1);
    mfma_gemm<bf16><<<gM, 256, 0, stream>>>(S5, Wvt, S0, 16384, 1024, 1024, 0, 0, 0, 0);
    conv_kernel<<<16384, 256, 0, stream>>>(S0, cv, S3, 0);
    mfma_gemm<bf16><<<gM, 256, 0, stream>>>(S5, Wgt, S0, 16384, 1024, 1024, 0, 0, 0, 0);
    beta_kernel<<<16384, 256, 0, stream>>>(x, Wb, p_beta);

    // Wbil -> per-head transposed bf16 (reuse attnB scratch; all Wqt..Wgt
    // reads are complete after the last mfma_gemm above)
    bf16* Wbilt = attnB;
    castTb_kernel<<<dim3(8, 8, 4), 256, 0, stream>>>(Wbil, Wbilt);
    // kproj = k @ Wbil[h] on MFMA: batched z=16, M=4096, N=256, K=256
    mfma_gemm<bf16><<<dim3(2, 32, 16), 256, 0, stream>>>(
        S2, Wbilt, S4, 4096, 256, 256, 1048576ull, 65536ull, 1048576ull, 3);
    chunk_kernel<<<1024, 512, 0, stream>>>(
        S2, S3, S1, p_beta, S4, fw1, fb1, fw2, fb2, temp,
        S5 /*u*/, S4 /*w*/, attnB, p_psi);
    ktr_kernel<<<1024, 256, 0, stream>>>(S2);    // k -> kT in place
    scan_kernel<<<256, 256, 0, stream>>>(
        S1, S2, S4, S5, attnB, p_psi, lamF, lamS, S3 /*o*/);
    // attnB free after scan: reuse for transposed-bf16 Wo
    castT_kernel<<<dim3(32, 32), 256, 0, stream>>>(Wo, attnB);
    fnorm_kernel<<<16384, 256, 0, stream>>>(S3, S0, rmsw, S1);
    mfma_gemm<float><<<gM, 256, 0, stream>>>(S1, attnB, out, 16384, 1024, 1024, 0, 0, 0, 0);
}